// Round 6
// baseline (3566.268 us; speedup 1.0000x reference)
//
#include <hip/hip_runtime.h>

// Decoder: B=16, T=128, V=32000, E=512, H=1024 (2 LSTM layers), CTX=2048.
// dec_seq_bf (primary): persistent 256 blocks x 512 threads, bf16 weights
//   (prep-converted into ws; halves footprint -> per-XCD L2 fit, L3-stable),
//   flat one-hop relaxed-poll barrier, x1 re-read via plain cached loads.
// dec_seq (fallback if ws_size too small): R5 fp32-weight path.
// fc_gemm_mfma: bf16 MFMA GEMM -> [16][128][32000] logits (~125us).

#define NBLK 256

typedef float f32x4 __attribute__((ext_vector_type(4)));
typedef __bf16 bf16x8 __attribute__((ext_vector_type(8)));
typedef unsigned short u16;

__device__ __forceinline__ float sigf(float x) { return 1.0f / (1.0f + __expf(-x)); }
__device__ __forceinline__ float tanh_(float x) {
  x = fminf(15.0f, fmaxf(-15.0f, x));
  float e = __expf(2.0f * x);
  return (e - 1.0f) / (e + 1.0f);
}

__device__ __forceinline__ u16 f2bf(float f) {
  __bf16 h = (__bf16)f;  // RNE
  return __builtin_bit_cast(u16, h);
}

// unpack 4 bf16 (packed low->high k order) to float4
__device__ __forceinline__ float4 bf2f(uint2 u) {
  float4 r;
  r.x = __builtin_bit_cast(float, u.x << 16);
  r.y = __builtin_bit_cast(float, u.x & 0xffff0000u);
  r.z = __builtin_bit_cast(float, u.y << 16);
  r.w = __builtin_bit_cast(float, u.y & 0xffff0000u);
  return r;
}

// Coherent (L2-bypass) scalar store: write-through to coherence point.
__device__ __forceinline__ void st_cv(float* p, float v) {
  asm volatile("global_store_dword %0, %1, off sc0 sc1" :: "v"(p), "v"(v) : "memory");
}

// 8 coherent dwordx4 loads in flight, one waitcnt.
__device__ __forceinline__ void ld8_cv(const float* a0, const float* a1, const float* a2,
                                       const float* a3, const float* a4, const float* a5,
                                       const float* a6, const float* a7,
                                       f32x4& v0, f32x4& v1, f32x4& v2, f32x4& v3,
                                       f32x4& v4, f32x4& v5, f32x4& v6, f32x4& v7) {
  asm volatile(
      "global_load_dwordx4 %0, %8, off sc0 sc1\n\t"
      "global_load_dwordx4 %1, %9, off sc0 sc1\n\t"
      "global_load_dwordx4 %2, %10, off sc0 sc1\n\t"
      "global_load_dwordx4 %3, %11, off sc0 sc1\n\t"
      "global_load_dwordx4 %4, %12, off sc0 sc1\n\t"
      "global_load_dwordx4 %5, %13, off sc0 sc1\n\t"
      "global_load_dwordx4 %6, %14, off sc0 sc1\n\t"
      "global_load_dwordx4 %7, %15, off sc0 sc1\n\t"
      "s_waitcnt vmcnt(0)"
      : "=&v"(v0), "=&v"(v1), "=&v"(v2), "=&v"(v3),
        "=&v"(v4), "=&v"(v5), "=&v"(v6), "=&v"(v7)
      : "v"(a0), "v"(a1), "v"(a2), "v"(a3), "v"(a4), "v"(a5), "v"(a6), "v"(a7)
      : "memory");
}

// Stage a 16x1024 float slab (64KB) src -> xls[0..15][dstoff..+1023] (bypass).
__device__ __forceinline__ void stage64k(const float* src, int dstoff, int tid,
                                         float xls[16][2052]) {
  f32x4 v0, v1, v2, v3, v4, v5, v6, v7;
  const float* s = src + 4 * tid;
  ld8_cv(s, s + 2048, s + 4096, s + 6144, s + 8192, s + 10240, s + 12288, s + 14336,
         v0, v1, v2, v3, v4, v5, v6, v7);
  const int bb = tid >> 8, k4 = (tid & 255) * 4;
  *(f32x4*)&xls[bb + 0][dstoff + k4] = v0;
  *(f32x4*)&xls[bb + 2][dstoff + k4] = v1;
  *(f32x4*)&xls[bb + 4][dstoff + k4] = v2;
  *(f32x4*)&xls[bb + 6][dstoff + k4] = v3;
  *(f32x4*)&xls[bb + 8][dstoff + k4] = v4;
  *(f32x4*)&xls[bb + 10][dstoff + k4] = v5;
  *(f32x4*)&xls[bb + 12][dstoff + k4] = v6;
  *(f32x4*)&xls[bb + 14][dstoff + k4] = v7;
}

// Same staging but PLAIN cached loads (safe only for written-once-then-read
// data within this launch, e.g. x1[t]; L2 amortizes across blocks per XCD).
__device__ __forceinline__ void stage64k_pl(const float* src, int dstoff, int tid,
                                            float xls[16][2052]) {
  const float* s = src + 4 * tid;
  f32x4 v0 = *(const f32x4*)(s);
  f32x4 v1 = *(const f32x4*)(s + 2048);
  f32x4 v2 = *(const f32x4*)(s + 4096);
  f32x4 v3 = *(const f32x4*)(s + 6144);
  f32x4 v4 = *(const f32x4*)(s + 8192);
  f32x4 v5 = *(const f32x4*)(s + 10240);
  f32x4 v6 = *(const f32x4*)(s + 12288);
  f32x4 v7 = *(const f32x4*)(s + 14336);
  const int bb = tid >> 8, k4 = (tid & 255) * 4;
  *(f32x4*)&xls[bb + 0][dstoff + k4] = v0;
  *(f32x4*)&xls[bb + 2][dstoff + k4] = v1;
  *(f32x4*)&xls[bb + 4][dstoff + k4] = v2;
  *(f32x4*)&xls[bb + 6][dstoff + k4] = v3;
  *(f32x4*)&xls[bb + 8][dstoff + k4] = v4;
  *(f32x4*)&xls[bb + 10][dstoff + k4] = v5;
  *(f32x4*)&xls[bb + 12][dstoff + k4] = v6;
  *(f32x4*)&xls[bb + 14][dstoff + k4] = v7;
}

// ---- R5 two-hop barrier (fallback path) ----
__device__ __forceinline__ void gsync(unsigned step, unsigned* bar) {
  __syncthreads();
  const int tid = threadIdx.x;
  if (blockIdx.x == 0) {
    if (tid < 64) {
      if (tid == 0) {
        asm volatile("s_waitcnt vmcnt(0)" ::: "memory");
        __hip_atomic_store(bar + 16, step, __ATOMIC_RELEASE, __HIP_MEMORY_SCOPE_AGENT);
      }
      const int base = 16 + tid * 64;
      for (;;) {
        bool mine = true;
#pragma unroll
        for (int j = 0; j < 4; ++j)
          mine &= (__hip_atomic_load(bar + base + j * 16, __ATOMIC_RELAXED,
                                     __HIP_MEMORY_SCOPE_AGENT) >= step);
        if (__all(mine)) break;
        __builtin_amdgcn_s_sleep(1);
      }
      asm volatile("" ::: "memory");
      if (tid == 0)
        __hip_atomic_store(bar, step, __ATOMIC_RELEASE, __HIP_MEMORY_SCOPE_AGENT);
    }
  } else {
    if (tid == 0) {
      asm volatile("s_waitcnt vmcnt(0)" ::: "memory");
      __hip_atomic_store(bar + 16 + blockIdx.x * 16, step, __ATOMIC_RELEASE,
                         __HIP_MEMORY_SCOPE_AGENT);
      while (__hip_atomic_load(bar, __ATOMIC_RELAXED, __HIP_MEMORY_SCOPE_AGENT) < step)
        __builtin_amdgcn_s_sleep(1);
      asm volatile("" ::: "memory");
    }
  }
  __syncthreads();
}

// ---- Flat one-hop barrier: every block's wave0 polls all 256 flags ----
__device__ __forceinline__ void gsyncf(unsigned step, unsigned* bar) {
  __syncthreads();
  const int tid = threadIdx.x;
  if (tid == 0) {
    asm volatile("s_waitcnt vmcnt(0)" ::: "memory");
    __hip_atomic_store(bar + 16 + blockIdx.x * 16, step, __ATOMIC_RELEASE,
                       __HIP_MEMORY_SCOPE_AGENT);
  }
  if (tid < 64) {
    const int base = 16 + tid * 64;  // 4 flags per lane
    for (;;) {
      bool mine = true;
#pragma unroll
      for (int j = 0; j < 4; ++j)
        mine &= (__hip_atomic_load(bar + base + j * 16, __ATOMIC_RELAXED,
                                   __HIP_MEMORY_SCOPE_AGENT) >= step);
      if (__all(mine)) break;
      __builtin_amdgcn_s_sleep(1);
    }
    asm volatile("" ::: "memory");
  }
  __syncthreads();
}

__device__ __forceinline__ void dot4(float& a, float4 wv, float4 xv) {
  a = fmaf(wv.x, xv.x, a);
  a = fmaf(wv.y, xv.y, a);
  a = fmaf(wv.z, xv.z, a);
  a = fmaf(wv.w, xv.w, a);
}

#define DECL_ACC                                                        \
  float acc00 = 0.f, acc01 = 0.f, acc02 = 0.f, acc03 = 0.f,             \
        acc10 = 0.f, acc11 = 0.f, acc12 = 0.f, acc13 = 0.f,             \
        acc20 = 0.f, acc21 = 0.f, acc22 = 0.f, acc23 = 0.f,             \
        acc30 = 0.f, acc31 = 0.f, acc32 = 0.f, acc33 = 0.f;

// fp32-weight K-step (fallback + INIT ctx projection)
#define KSTEP(p0, p1, p2, p3, K4)                                       \
  {                                                                     \
    const float4 xv0 = *(const float4*)&xls[bq4][(K4)];                 \
    const float4 xv1 = *(const float4*)&xls[bq4 + 1][(K4)];             \
    const float4 xv2 = *(const float4*)&xls[bq4 + 2][(K4)];             \
    const float4 xv3 = *(const float4*)&xls[bq4 + 3][(K4)];             \
    float4 wv;                                                          \
    wv = *(const float4*)(p0);                                          \
    dot4(acc00, wv, xv0); dot4(acc01, wv, xv1);                         \
    dot4(acc02, wv, xv2); dot4(acc03, wv, xv3);                         \
    wv = *(const float4*)(p1);                                          \
    dot4(acc10, wv, xv0); dot4(acc11, wv, xv1);                         \
    dot4(acc12, wv, xv2); dot4(acc13, wv, xv3);                         \
    wv = *(const float4*)(p2);                                          \
    dot4(acc20, wv, xv0); dot4(acc21, wv, xv1);                         \
    dot4(acc22, wv, xv2); dot4(acc23, wv, xv3);                         \
    wv = *(const float4*)(p3);                                          \
    dot4(acc30, wv, xv0); dot4(acc31, wv, xv1);                         \
    dot4(acc32, wv, xv2); dot4(acc33, wv, xv3);                         \
  }

// bf16-weight double K-step: covers x/k chunks [XK,XK+128) and [XK+128,XK+256)
// per lane-4 slice; weight k = WK-based (row-major bf16). Loads are uint2
// (8B/lane, 256B/wave contiguous); x-LDS pattern identical to KSTEP.
#define KSTEPB(q0, q1, q2, q3, XK, WK)                                  \
  {                                                                     \
    const int xk = (XK) + kc * 4;                                       \
    const int wk = (WK) + kc * 4;                                       \
    const float4 xa0 = *(const float4*)&xls[bq4][xk];                   \
    const float4 xa1 = *(const float4*)&xls[bq4 + 1][xk];               \
    const float4 xa2 = *(const float4*)&xls[bq4 + 2][xk];               \
    const float4 xa3 = *(const float4*)&xls[bq4 + 3][xk];               \
    const float4 xb0 = *(const float4*)&xls[bq4][xk + 128];             \
    const float4 xb1 = *(const float4*)&xls[bq4 + 1][xk + 128];         \
    const float4 xb2 = *(const float4*)&xls[bq4 + 2][xk + 128];         \
    const float4 xb3 = *(const float4*)&xls[bq4 + 3][xk + 128];         \
    uint2 ua, ub; float4 wv;                                            \
    ua = *(const uint2*)((q0) + wk); ub = *(const uint2*)((q0) + wk + 128); \
    wv = bf2f(ua);                                                      \
    dot4(acc00, wv, xa0); dot4(acc01, wv, xa1);                         \
    dot4(acc02, wv, xa2); dot4(acc03, wv, xa3);                         \
    wv = bf2f(ub);                                                      \
    dot4(acc00, wv, xb0); dot4(acc01, wv, xb1);                         \
    dot4(acc02, wv, xb2); dot4(acc03, wv, xb3);                         \
    ua = *(const uint2*)((q1) + wk); ub = *(const uint2*)((q1) + wk + 128); \
    wv = bf2f(ua);                                                      \
    dot4(acc10, wv, xa0); dot4(acc11, wv, xa1);                         \
    dot4(acc12, wv, xa2); dot4(acc13, wv, xa3);                         \
    wv = bf2f(ub);                                                      \
    dot4(acc10, wv, xb0); dot4(acc11, wv, xb1);                         \
    dot4(acc12, wv, xb2); dot4(acc13, wv, xb3);                         \
    ua = *(const uint2*)((q2) + wk); ub = *(const uint2*)((q2) + wk + 128); \
    wv = bf2f(ua);                                                      \
    dot4(acc20, wv, xa0); dot4(acc21, wv, xa1);                         \
    dot4(acc22, wv, xa2); dot4(acc23, wv, xa3);                         \
    wv = bf2f(ub);                                                      \
    dot4(acc20, wv, xb0); dot4(acc21, wv, xb1);                         \
    dot4(acc22, wv, xb2); dot4(acc23, wv, xb3);                         \
    ua = *(const uint2*)((q3) + wk); ub = *(const uint2*)((q3) + wk + 128); \
    wv = bf2f(ua);                                                      \
    dot4(acc30, wv, xa0); dot4(acc31, wv, xa1);                         \
    dot4(acc32, wv, xa2); dot4(acc33, wv, xa3);                         \
    wv = bf2f(ub);                                                      \
    dot4(acc30, wv, xb0); dot4(acc31, wv, xb1);                         \
    dot4(acc32, wv, xb2); dot4(acc33, wv, xb3);                         \
  }

#define RED5(v)                \
  {                            \
    v += __shfl_xor(v, 1);     \
    v += __shfl_xor(v, 2);     \
    v += __shfl_xor(v, 4);     \
    v += __shfl_xor(v, 8);     \
    v += __shfl_xor(v, 16);    \
  }

#define REDUCE_ALL                                                     \
  {                                                                    \
    RED5(acc00) RED5(acc01) RED5(acc02) RED5(acc03)                    \
    RED5(acc10) RED5(acc11) RED5(acc12) RED5(acc13)                    \
    RED5(acc20) RED5(acc21) RED5(acc22) RED5(acc23)                    \
    RED5(acc30) RED5(acc31) RED5(acc32) RED5(acc33)                    \
  }

#define WRITE_GLS                                                                   \
  {                                                                                 \
    if (kc == 0) {                                                                  \
      gls[jq][0][bq4] = acc00; gls[jq][0][bq4 + 1] = acc01;                         \
      gls[jq][0][bq4 + 2] = acc02; gls[jq][0][bq4 + 3] = acc03;                     \
      gls[jq][1][bq4] = acc10; gls[jq][1][bq4 + 1] = acc11;                         \
      gls[jq][1][bq4 + 2] = acc12; gls[jq][1][bq4 + 3] = acc13;                     \
      gls[jq][2][bq4] = acc20; gls[jq][2][bq4 + 1] = acc21;                         \
      gls[jq][2][bq4 + 2] = acc22; gls[jq][2][bq4 + 3] = acc23;                     \
      gls[jq][3][bq4] = acc30; gls[jq][3][bq4 + 1] = acc31;                         \
      gls[jq][3][bq4 + 2] = acc32; gls[jq][3][bq4 + 3] = acc33;                     \
    }                                                                               \
  }

// fp32 -> bf16 weight conversion (per launch; ~25us for 92MB)
__global__ void prep_bf16(const float* __restrict__ src, u16* __restrict__ dst, int n8) {
  for (int i = blockIdx.x * blockDim.x + threadIdx.x; i < n8; i += gridDim.x * blockDim.x) {
    float4 a = *(const float4*)(src + (size_t)i * 8);
    float4 b = *(const float4*)(src + (size_t)i * 8 + 4);
    __align__(16) u16 r[8] = {f2bf(a.x), f2bf(a.y), f2bf(a.z), f2bf(a.w),
                              f2bf(b.x), f2bf(b.y), f2bf(b.z), f2bf(b.w)};
    *(uint4*)(dst + (size_t)i * 8) = *(uint4*)r;
  }
}

// ---------------- primary: bf16-weight persistent decoder ----------------
__global__ __launch_bounds__(512, 2) void dec_seq_bf(
    const float* __restrict__ enc_h, const float* __restrict__ enc_c,
    const int* __restrict__ tgt, const float* __restrict__ emb,
    const float* __restrict__ wih0, const float* __restrict__ bih0,
    const float* __restrict__ bhh0, const float* __restrict__ bih1,
    const float* __restrict__ bhh1,
    const u16* __restrict__ wb_ih0, const u16* __restrict__ wb_hh0,
    const u16* __restrict__ wb_ih1, const u16* __restrict__ wb_hh1,
    float* __restrict__ h0b, float* __restrict__ h1b,
    float* __restrict__ x1, u16* __restrict__ out2b,
    unsigned* bar) {
  __shared__ float xls[16][2052];
  __shared__ float gls[4][4][16];

  const int tid = threadIdx.x;
  const int wgid = blockIdx.x;
  const int kc = tid & 31;
  const int combo = tid >> 5;
  const int jq = combo >> 2;
  const int bq4 = (combo & 3) * 4;
  const int w4 = wgid * 4;
  unsigned step = 0;

  const int j0 = jq * 1024 + w4;
  // fp32 rows (INIT ctx projection only)
  const float* wih0r0 = wih0 + (size_t)(j0 + 0) * 2560;
  const float* wih0r1 = wih0 + (size_t)(j0 + 1) * 2560;
  const float* wih0r2 = wih0 + (size_t)(j0 + 2) * 2560;
  const float* wih0r3 = wih0 + (size_t)(j0 + 3) * 2560;
  // bf16 rows (hot loop)
  const u16* qih0r0 = wb_ih0 + (size_t)(j0 + 0) * 2560;
  const u16* qih0r1 = wb_ih0 + (size_t)(j0 + 1) * 2560;
  const u16* qih0r2 = wb_ih0 + (size_t)(j0 + 2) * 2560;
  const u16* qih0r3 = wb_ih0 + (size_t)(j0 + 3) * 2560;
  const u16* qhh0r0 = wb_hh0 + (size_t)(j0 + 0) * 1024;
  const u16* qhh0r1 = wb_hh0 + (size_t)(j0 + 1) * 1024;
  const u16* qhh0r2 = wb_hh0 + (size_t)(j0 + 2) * 1024;
  const u16* qhh0r3 = wb_hh0 + (size_t)(j0 + 3) * 1024;
  const u16* qih1r0 = wb_ih1 + (size_t)(j0 + 0) * 1024;
  const u16* qih1r1 = wb_ih1 + (size_t)(j0 + 1) * 1024;
  const u16* qih1r2 = wb_ih1 + (size_t)(j0 + 2) * 1024;
  const u16* qih1r3 = wb_ih1 + (size_t)(j0 + 3) * 1024;
  const u16* qhh1r0 = wb_hh1 + (size_t)(j0 + 0) * 1024;
  const u16* qhh1r1 = wb_hh1 + (size_t)(j0 + 1) * 1024;
  const u16* qhh1r2 = wb_hh1 + (size_t)(j0 + 2) * 1024;
  const u16* qhh1r3 = wb_hh1 + (size_t)(j0 + 3) * 1024;

  const int gdj = tid >> 4;
  const int gb = tid & 15;
  float cpA0 = 0.f, cpA1 = 0.f, cpA2 = 0.f, cpA3 = 0.f;
  float cpB0 = 0.f, cpB1 = 0.f, cpB2 = 0.f, cpB3 = 0.f;
  float c0r = 0.f, c1r = 0.f;

  // ---------------- INIT: ctx projection (fp32) + biases + h/c ----------------
#pragma unroll
  for (int c = 0; c < 16; ++c) {
    int f4 = tid + c * 512;
    int b = f4 >> 9, kq = f4 & 511;
    const float4 v = *(const float4*)(enc_h + (kq >> 7) * 8192 + b * 512 + (kq & 127) * 4);
    *(float4*)&xls[b][kq * 4] = v;
  }
  __syncthreads();
  {
    DECL_ACC
#pragma unroll 4
    for (int i = 0; i < 16; ++i) {
      const int k4 = i * 128 + kc * 4;
      KSTEP(wih0r0 + 512 + k4, wih0r1 + 512 + k4, wih0r2 + 512 + k4, wih0r3 + 512 + k4, k4)
    }
    REDUCE_ALL
    WRITE_GLS
  }
  __syncthreads();
  if (tid < 64) {
    const int jp = w4 + gdj;
    cpA0 = gls[0][gdj][gb] + bih0[jp] + bhh0[jp];
    cpA1 = gls[1][gdj][gb] + bih0[1024 + jp] + bhh0[1024 + jp];
    cpA2 = gls[2][gdj][gb] + bih0[2048 + jp] + bhh0[2048 + jp];
    cpA3 = gls[3][gdj][gb] + bih0[3072 + jp] + bhh0[3072 + jp];
    cpB0 = bih1[jp] + bhh1[jp];
    cpB1 = bih1[1024 + jp] + bhh1[1024 + jp];
    cpB2 = bih1[2048 + jp] + bhh1[2048 + jp];
    cpB3 = bih1[3072 + jp] + bhh1[3072 + jp];
    const int dir = jp >> 9, e = jp & 511;
    c0r = enc_c[dir * 8192 + gb * 512 + e];
    c1r = enc_c[(2 + dir) * 8192 + gb * 512 + e];
    st_cv(h0b + gb * 1024 + jp, enc_h[dir * 8192 + gb * 512 + e]);
    st_cv(h1b + gb * 1024 + jp, enc_h[(2 + dir) * 8192 + gb * 512 + e]);
  }
  gsyncf(++step, bar);

  // ---------------- LAYER 0: K = 512 (emb) + 1024 (h), bf16 weights ----------------
  int cur = 0;
  for (int t = 0; t < 128; ++t) {
#pragma unroll
    for (int c = 0; c < 4; ++c) {
      int f4 = tid + c * 512;
      int b = f4 >> 7, kq = f4 & 127;
      int tok = (t == 0) ? 1 : tgt[b * 128 + (t - 1)];
      const float4 v = *(const float4*)(emb + (size_t)tok * 512 + kq * 4);
      *(float4*)&xls[b][kq * 4] = v;
    }
    stage64k(h0b + cur * 16384, 512, tid, xls);
    __syncthreads();
    {
      DECL_ACC
      KSTEPB(qih0r0, qih0r1, qih0r2, qih0r3, 0, 0)
      KSTEPB(qih0r0, qih0r1, qih0r2, qih0r3, 256, 256)
      KSTEPB(qhh0r0, qhh0r1, qhh0r2, qhh0r3, 512, 0)
      KSTEPB(qhh0r0, qhh0r1, qhh0r2, qhh0r3, 768, 256)
      KSTEPB(qhh0r0, qhh0r1, qhh0r2, qhh0r3, 1024, 512)
      KSTEPB(qhh0r0, qhh0r1, qhh0r2, qhh0r3, 1280, 768)
      REDUCE_ALL
      WRITE_GLS
    }
    __syncthreads();
    if (tid < 64) {
      const int jp = w4 + gdj;
      float gi = gls[0][gdj][gb] + cpA0;
      float gf = gls[1][gdj][gb] + cpA1;
      float gg = gls[2][gdj][gb] + cpA2;
      float go = gls[3][gdj][gb] + cpA3;
      c0r = sigf(gf) * c0r + sigf(gi) * tanh_(gg);
      float h = sigf(go) * tanh_(c0r);
      st_cv(h0b + (cur ^ 1) * 16384 + gb * 1024 + jp, h);
      st_cv(x1 + t * 16384 + gb * 1024 + jp, h);
    }
    gsyncf(++step, bar);
    cur ^= 1;
  }

  // ---------------- LAYER 1: K = 1024 (x1) + 1024 (h), bf16 weights ----------------
  int cur2 = 0;
  for (int t = 0; t < 128; ++t) {
    stage64k_pl(x1 + t * 16384, 0, tid, xls);       // written once, plain cached
    stage64k(h1b + cur2 * 16384, 1024, tid, xls);   // rewritten each step, bypass
    __syncthreads();
    {
      DECL_ACC
      KSTEPB(qih1r0, qih1r1, qih1r2, qih1r3, 0, 0)
      KSTEPB(qih1r0, qih1r1, qih1r2, qih1r3, 256, 256)
      KSTEPB(qih1r0, qih1r1, qih1r2, qih1r3, 512, 512)
      KSTEPB(qih1r0, qih1r1, qih1r2, qih1r3, 768, 768)
      KSTEPB(qhh1r0, qhh1r1, qhh1r2, qhh1r3, 1024, 0)
      KSTEPB(qhh1r0, qhh1r1, qhh1r2, qhh1r3, 1280, 256)
      KSTEPB(qhh1r0, qhh1r1, qhh1r2, qhh1r3, 1536, 512)
      KSTEPB(qhh1r0, qhh1r1, qhh1r2, qhh1r3, 1792, 768)
      REDUCE_ALL
      WRITE_GLS
    }
    __syncthreads();
    if (tid < 64) {
      const int jp = w4 + gdj;
      float gi = gls[0][gdj][gb] + cpB0;
      float gf = gls[1][gdj][gb] + cpB1;
      float gg = gls[2][gdj][gb] + cpB2;
      float go = gls[3][gdj][gb] + cpB3;
      c1r = sigf(gf) * c1r + sigf(gi) * tanh_(gg);
      float h = sigf(go) * tanh_(c1r);
      st_cv(h1b + (cur2 ^ 1) * 16384 + gb * 1024 + jp, h);
      out2b[(t * 16 + gb) * 1024 + jp] = f2bf(tanh_(h));
    }
    gsyncf(++step, bar);
    cur2 ^= 1;
  }
}

// ---------------- fallback: R5 fp32-weight decoder (unchanged) ----------------
__global__ __launch_bounds__(512, 2) void dec_seq(
    const float* __restrict__ enc_h, const float* __restrict__ enc_c,
    const int* __restrict__ tgt, const float* __restrict__ emb,
    const float* __restrict__ wih0, const float* __restrict__ whh0,
    const float* __restrict__ bih0, const float* __restrict__ bhh0,
    const float* __restrict__ wih1, const float* __restrict__ whh1,
    const float* __restrict__ bih1, const float* __restrict__ bhh1,
    float* __restrict__ h0b, float* __restrict__ h1b,
    float* __restrict__ x1, u16* __restrict__ out2b,
    unsigned* bar) {
  __shared__ float xls[16][2052];
  __shared__ float gls[4][4][16];

  const int tid = threadIdx.x;
  const int wgid = blockIdx.x;
  const int kc = tid & 31;
  const int combo = tid >> 5;
  const int jq = combo >> 2;
  const int bq4 = (combo & 3) * 4;
  const int w4 = wgid * 4;
  unsigned step = 0;

  const int j0 = jq * 1024 + w4;
  const float* wih0r0 = wih0 + (size_t)(j0 + 0) * 2560;
  const float* wih0r1 = wih0 + (size_t)(j0 + 1) * 2560;
  const float* wih0r2 = wih0 + (size_t)(j0 + 2) * 2560;
  const float* wih0r3 = wih0 + (size_t)(j0 + 3) * 2560;
  const float* whh0r0 = whh0 + (size_t)(j0 + 0) * 1024;
  const float* whh0r1 = whh0 + (size_t)(j0 + 1) * 1024;
  const float* whh0r2 = whh0 + (size_t)(j0 + 2) * 1024;
  const float* whh0r3 = whh0 + (size_t)(j0 + 3) * 1024;
  const float* wih1r0 = wih1 + (size_t)(j0 + 0) * 1024;
  const float* wih1r1 = wih1 + (size_t)(j0 + 1) * 1024;
  const float* wih1r2 = wih1 + (size_t)(j0 + 2) * 1024;
  const float* wih1r3 = wih1 + (size_t)(j0 + 3) * 1024;
  const float* whh1r0 = whh1 + (size_t)(j0 + 0) * 1024;
  const float* whh1r1 = whh1 + (size_t)(j0 + 1) * 1024;
  const float* whh1r2 = whh1 + (size_t)(j0 + 2) * 1024;
  const float* whh1r3 = whh1 + (size_t)(j0 + 3) * 1024;

  const int gdj = tid >> 4;
  const int gb = tid & 15;
  float cpA0 = 0.f, cpA1 = 0.f, cpA2 = 0.f, cpA3 = 0.f;
  float cpB0 = 0.f, cpB1 = 0.f, cpB2 = 0.f, cpB3 = 0.f;
  float c0r = 0.f, c1r = 0.f;

#pragma unroll
  for (int c = 0; c < 16; ++c) {
    int f4 = tid + c * 512;
    int b = f4 >> 9, kq = f4 & 511;
    const float4 v = *(const float4*)(enc_h + (kq >> 7) * 8192 + b * 512 + (kq & 127) * 4);
    *(float4*)&xls[b][kq * 4] = v;
  }
  __syncthreads();
  {
    DECL_ACC
#pragma unroll 4
    for (int i = 0; i < 16; ++i) {
      const int k4 = i * 128 + kc * 4;
      KSTEP(wih0r0 + 512 + k4, wih0r1 + 512 + k4, wih0r2 + 512 + k4, wih0r3 + 512 + k4, k4)
    }
    REDUCE_ALL
    WRITE_GLS
  }
  __syncthreads();
  if (tid < 64) {
    const int jp = w4 + gdj;
    cpA0 = gls[0][gdj][gb] + bih0[jp] + bhh0[jp];
    cpA1 = gls[1][gdj][gb] + bih0[1024 + jp] + bhh0[1024 + jp];
    cpA2 = gls[2][gdj][gb] + bih0[2048 + jp] + bhh0[2048 + jp];
    cpA3 = gls[3][gdj][gb] + bih0[3072 + jp] + bhh0[3072 + jp];
    cpB0 = bih1[jp] + bhh1[jp];
    cpB1 = bih1[1024 + jp] + bhh1[1024 + jp];
    cpB2 = bih1[2048 + jp] + bhh1[2048 + jp];
    cpB3 = bih1[3072 + jp] + bhh1[3072 + jp];
    const int dir = jp >> 9, e = jp & 511;
    c0r = enc_c[dir * 8192 + gb * 512 + e];
    c1r = enc_c[(2 + dir) * 8192 + gb * 512 + e];
    st_cv(h0b + gb * 1024 + jp, enc_h[dir * 8192 + gb * 512 + e]);
    st_cv(h1b + gb * 1024 + jp, enc_h[(2 + dir) * 8192 + gb * 512 + e]);
  }
  gsync(++step, bar);

  int cur = 0;
  for (int t = 0; t < 128; ++t) {
#pragma unroll
    for (int c = 0; c < 4; ++c) {
      int f4 = tid + c * 512;
      int b = f4 >> 7, kq = f4 & 127;
      int tok = (t == 0) ? 1 : tgt[b * 128 + (t - 1)];
      const float4 v = *(const float4*)(emb + (size_t)tok * 512 + kq * 4);
      *(float4*)&xls[b][kq * 4] = v;
    }
    stage64k(h0b + cur * 16384, 512, tid, xls);
    __syncthreads();
    {
      DECL_ACC
#pragma unroll 4
      for (int i = 0; i < 4; ++i) {
        const int k4 = i * 128 + kc * 4;
        KSTEP(wih0r0 + k4, wih0r1 + k4, wih0r2 + k4, wih0r3 + k4, k4)
      }
#pragma unroll 4
      for (int i = 4; i < 12; ++i) {
        const int k4 = i * 128 + kc * 4;
        const int kh = k4 - 512;
        KSTEP(whh0r0 + kh, whh0r1 + kh, whh0r2 + kh, whh0r3 + kh, k4)
      }
      REDUCE_ALL
      WRITE_GLS
    }
    __syncthreads();
    if (tid < 64) {
      const int jp = w4 + gdj;
      float gi = gls[0][gdj][gb] + cpA0;
      float gf = gls[1][gdj][gb] + cpA1;
      float gg = gls[2][gdj][gb] + cpA2;
      float go = gls[3][gdj][gb] + cpA3;
      c0r = sigf(gf) * c0r + sigf(gi) * tanh_(gg);
      float h = sigf(go) * tanh_(c0r);
      st_cv(h0b + (cur ^ 1) * 16384 + gb * 1024 + jp, h);
      st_cv(x1 + t * 16384 + gb * 1024 + jp, h);
    }
    gsync(++step, bar);
    cur ^= 1;
  }

  int cur2 = 0;
  for (int t = 0; t < 128; ++t) {
    stage64k(x1 + t * 16384, 0, tid, xls);
    stage64k(h1b + cur2 * 16384, 1024, tid, xls);
    __syncthreads();
    {
      DECL_ACC
#pragma unroll 4
      for (int i = 0; i < 8; ++i) {
        const int k4 = i * 128 + kc * 4;
        KSTEP(wih1r0 + k4, wih1r1 + k4, wih1r2 + k4, wih1r3 + k4, k4)
      }
#pragma unroll 4
      for (int i = 8; i < 16; ++i) {
        const int k4 = i * 128 + kc * 4;
        const int kh = k4 - 1024;
        KSTEP(whh1r0 + kh, whh1r1 + kh, whh1r2 + kh, whh1r3 + kh, k4)
      }
      REDUCE_ALL
      WRITE_GLS
    }
    __syncthreads();
    if (tid < 64) {
      const int jp = w4 + gdj;
      float gi = gls[0][gdj][gb] + cpB0;
      float gf = gls[1][gdj][gb] + cpB1;
      float gg = gls[2][gdj][gb] + cpB2;
      float go = gls[3][gdj][gb] + cpB3;
      c1r = sigf(gf) * c1r + sigf(gi) * tanh_(gg);
      float h = sigf(go) * tanh_(c1r);
      st_cv(h1b + (cur2 ^ 1) * 16384 + gb * 1024 + jp, h);
      out2b[(t * 16 + gb) * 1024 + jp] = f2bf(tanh_(h));
    }
    gsync(++step, bar);
    cur2 ^= 1;
  }
}

// logits GEMM: A bf16 [2048][1024]; B fp32 [32000][1024] (cvt per tile); C fp32.
__global__ __launch_bounds__(256, 2) void fc_gemm_mfma(
    const u16* __restrict__ A, const float* __restrict__ Bw,
    const float* __restrict__ bias, float* __restrict__ C) {
  __shared__ __align__(16) u16 Al[128][40];
  __shared__ __align__(16) u16 Bl[128][40];

  const int tid = threadIdx.x;
  const int m0 = blockIdx.x * 128;
  const int n0 = blockIdx.y * 128;
  const int wave = tid >> 6;
  const int lane = tid & 63;
  const int wm = (wave & 1) * 64;
  const int wn = (wave >> 1) * 64;
  const int fr = lane & 15;
  const int ks = lane >> 4;

  const int srow = tid >> 1;
  const int sh16 = (tid & 1) * 16;

  const u16* Ag = A + (size_t)(m0 + srow) * 1024 + sh16;
  const float* Bg = Bw + (size_t)(n0 + srow) * 1024 + sh16;

  f32x4 acc[4][4] = {};

  for (int k0 = 0; k0 < 1024; k0 += 32) {
    uint4 a0 = *(const uint4*)(Ag + k0);
    uint4 a1 = *(const uint4*)(Ag + k0 + 8);
    float bfv[16];
    *(float4*)&bfv[0] = *(const float4*)(Bg + k0);
    *(float4*)&bfv[4] = *(const float4*)(Bg + k0 + 4);
    *(float4*)&bfv[8] = *(const float4*)(Bg + k0 + 8);
    *(float4*)&bfv[12] = *(const float4*)(Bg + k0 + 12);
    u16 bu[16];
#pragma unroll
    for (int u = 0; u < 16; ++u) bu[u] = f2bf(bfv[u]);

    __syncthreads();
    *(uint4*)&Al[srow][sh16] = a0;
    *(uint4*)&Al[srow][sh16 + 8] = a1;
    *(uint4*)&Bl[srow][sh16] = *(uint4*)&bu[0];
    *(uint4*)&Bl[srow][sh16 + 8] = *(uint4*)&bu[8];
    __syncthreads();

    bf16x8 af[4], bf[4];
#pragma unroll
    for (int i = 0; i < 4; ++i) af[i] = *(const bf16x8*)&Al[wm + i * 16 + fr][ks * 8];
#pragma unroll
    for (int j = 0; j < 4; ++j) bf[j] = *(const bf16x8*)&Bl[wn + j * 16 + fr][ks * 8];
#pragma unroll
    for (int i = 0; i < 4; ++i)
#pragma unroll
      for (int j = 0; j < 4; ++j)
        acc[i][j] = __builtin_amdgcn_mfma_f32_16x16x32_bf16(af[i], bf[j], acc[i][j], 0, 0, 0);
  }

  float bj[4];
#pragma unroll
  for (int j = 0; j < 4; ++j) bj[j] = bias[n0 + wn + j * 16 + fr];

  const int mrb = (lane >> 4) * 4;
#pragma unroll
  for (int i = 0; i < 4; ++i) {
#pragma unroll
    for (int r = 0; r < 4; ++r) {
      const int m = m0 + wm + i * 16 + mrb + r;
      float* dst = C + ((size_t)(m & 15) * 128 + (m >> 4)) * 32000;
#pragma unroll
      for (int j = 0; j < 4; ++j) {
        dst[n0 + wn + j * 16 + fr] = acc[i][j][r] + bj[j];
      }
    }
  }
}

extern "C" void kernel_launch(void* const* d_in, const int* in_sizes, int n_in,
                              void* d_out, int out_size, void* d_ws, size_t ws_size,
                              hipStream_t stream) {
  const float* enc_h = (const float*)d_in[0];
  const float* enc_c = (const float*)d_in[1];
  const int* tgt = (const int*)d_in[2];
  const float* emb = (const float*)d_in[3];
  const float* wih0 = (const float*)d_in[4];
  const float* whh0 = (const float*)d_in[5];
  const float* bih0 = (const float*)d_in[6];
  const float* bhh0 = (const float*)d_in[7];
  const float* wih1 = (const float*)d_in[8];
  const float* whh1 = (const float*)d_in[9];
  const float* bih1 = (const float*)d_in[10];
  const float* bhh1 = (const float*)d_in[11];
  const float* fcw = (const float*)d_in[12];
  const float* fcb = (const float*)d_in[13];
  float* logits = (float*)d_out;

  unsigned* bar = (unsigned*)d_ws;  // 32 KB barrier region
  hipMemsetAsync(d_ws, 0, 64 + 256 * 64, stream);

  // bf16 path needs: 32KB + 46.1MB weights + 256KB h + 8MB x1 + 4MB out2b
  if (ws_size >= 59200000ull) {
    u16* wb_ih0 = (u16*)((char*)d_ws + 32768);
    u16* wb_hh0 = wb_ih0 + 10485760;   // 4096*2560
    u16* wb_ih1 = wb_hh0 + 4194304;    // 4096*1024
    u16* wb_hh1 = wb_ih1 + 4194304;
    float* h0b = (float*)(wb_hh1 + 4194304);
    float* h1b = h0b + 32768;
    float* x1 = h1b + 32768;
    u16* out2b = (u16*)(x1 + 2097152);

    prep_bf16<<<2048, 256, 0, stream>>>(wih0, wb_ih0, 1310720);
    prep_bf16<<<2048, 256, 0, stream>>>(whh0, wb_hh0, 524288);
    prep_bf16<<<2048, 256, 0, stream>>>(wih1, wb_ih1, 524288);
    prep_bf16<<<2048, 256, 0, stream>>>(whh1, wb_hh1, 524288);
    dec_seq_bf<<<NBLK, 512, 0, stream>>>(enc_h, enc_c, tgt, emb, wih0, bih0, bhh0,
                                         bih1, bhh1, wb_ih0, wb_hh0, wb_ih1, wb_hh1,
                                         h0b, h1b, x1, out2b, bar);
    fc_gemm_mfma<<<dim3(16, 250), 256, 0, stream>>>(out2b, fcw, fcb, logits);
  } else {
    float* wsf = (float*)((char*)d_ws + 32768);
    float* h0b = wsf;
    float* h1b = wsf + 32768;
    float* x1 = wsf + 65536;
    u16* out2b = (u16*)(x1 + 2097152);
    dec_seq<<<NBLK, 512, 0, stream>>>(enc_h, enc_c, tgt, emb, wih0, whh0, bih0, bhh0,
                                      wih1, whh1, bih1, bhh1, h0b, h1b, x1, out2b, bar);
    fc_gemm_mfma<<<dim3(16, 250), 256, 0, stream>>>(out2b, fcw, fcb, logits);
  }
}

// Round 7
// 3161.143 us; speedup vs baseline: 1.1282x; 1.1282x over previous
//
#include <hip/hip_runtime.h>

// Decoder: B=16, T=128, V=32000, E=512, H=1024 (2 LSTM layers), CTX=2048.
// dec_seq_pl: persistent 256 blocks x 512 threads, bf16 weights (prep kernel),
//   CROSS-LAYER PIPELINED: macro-step s computes L0[t=s] and L1[t=s-1] with a
//   single grid barrier (257 -> 130 barriers).
//   Barrier is pure-asm: sc0/sc1 write-through stores + bypass poll loads,
//   NO HIP atomics (acquire emitted buffer_inv [R3], release likely emits
//   buffer_wbl2 -- both are per-step L2 maintenance storms).
// fc_gemm_mfma: bf16 MFMA GEMM -> [16][128][32000] logits (~125us).

#define NBLK 256

typedef float f32x4 __attribute__((ext_vector_type(4)));
typedef __bf16 bf16x8 __attribute__((ext_vector_type(8)));
typedef unsigned short u16;

__device__ __forceinline__ float sigf(float x) { return 1.0f / (1.0f + __expf(-x)); }
__device__ __forceinline__ float tanh_(float x) {
  x = fminf(15.0f, fmaxf(-15.0f, x));
  float e = __expf(2.0f * x);
  return (e - 1.0f) / (e + 1.0f);
}

__device__ __forceinline__ u16 f2bf(float f) {
  __bf16 h = (__bf16)f;  // RNE
  return __builtin_bit_cast(u16, h);
}

// unpack 4 bf16 (packed low->high k order) to float4
__device__ __forceinline__ float4 bf2f(uint2 u) {
  float4 r;
  r.x = __builtin_bit_cast(float, u.x << 16);
  r.y = __builtin_bit_cast(float, u.x & 0xffff0000u);
  r.z = __builtin_bit_cast(float, u.y << 16);
  r.w = __builtin_bit_cast(float, u.y & 0xffff0000u);
  return r;
}

// Coherent (write-through) scalar store.
__device__ __forceinline__ void st_cv(float* p, float v) {
  asm volatile("global_store_dword %0, %1, off sc0 sc1" :: "v"(p), "v"(v) : "memory");
}

// Flag publish: drain own data stores (ack at coherence point), then store flag.
// Plain sc0/sc1 store -- no atomic lowering, no buffer_wbl2.
__device__ __forceinline__ void flag_store(unsigned* p, unsigned v) {
  asm volatile(
      "s_waitcnt vmcnt(0)\n\t"
      "global_store_dword %0, %1, off sc0 sc1"
      :: "v"(p), "v"(v) : "memory");
}

// 4 bypass flag loads in flight, one waitcnt. No atomic lowering, no buffer_inv.
__device__ __forceinline__ void ld4_flags(const unsigned* p, unsigned& a, unsigned& b,
                                          unsigned& c, unsigned& d) {
  asm volatile(
      "global_load_dword %0, %4, off sc0 sc1\n\t"
      "global_load_dword %1, %5, off sc0 sc1\n\t"
      "global_load_dword %2, %6, off sc0 sc1\n\t"
      "global_load_dword %3, %7, off sc0 sc1\n\t"
      "s_waitcnt vmcnt(0)"
      : "=&v"(a), "=&v"(b), "=&v"(c), "=&v"(d)
      : "v"(p), "v"(p + 16), "v"(p + 32), "v"(p + 48)
      : "memory");
}

// 8 coherent dwordx4 loads in flight, one waitcnt.
__device__ __forceinline__ void ld8_cv(const float* a0, const float* a1, const float* a2,
                                       const float* a3, const float* a4, const float* a5,
                                       const float* a6, const float* a7,
                                       f32x4& v0, f32x4& v1, f32x4& v2, f32x4& v3,
                                       f32x4& v4, f32x4& v5, f32x4& v6, f32x4& v7) {
  asm volatile(
      "global_load_dwordx4 %0, %8, off sc0 sc1\n\t"
      "global_load_dwordx4 %1, %9, off sc0 sc1\n\t"
      "global_load_dwordx4 %2, %10, off sc0 sc1\n\t"
      "global_load_dwordx4 %3, %11, off sc0 sc1\n\t"
      "global_load_dwordx4 %4, %12, off sc0 sc1\n\t"
      "global_load_dwordx4 %5, %13, off sc0 sc1\n\t"
      "global_load_dwordx4 %6, %14, off sc0 sc1\n\t"
      "global_load_dwordx4 %7, %15, off sc0 sc1\n\t"
      "s_waitcnt vmcnt(0)"
      : "=&v"(v0), "=&v"(v1), "=&v"(v2), "=&v"(v3),
        "=&v"(v4), "=&v"(v5), "=&v"(v6), "=&v"(v7)
      : "v"(a0), "v"(a1), "v"(a2), "v"(a3), "v"(a4), "v"(a5), "v"(a6), "v"(a7)
      : "memory");
}

// Stage a 16x1024 float slab (64KB) src -> xls[0..15][dstoff..+1023] (bypass).
__device__ __forceinline__ void stage64k(const float* src, int dstoff, int tid,
                                         float xls[16][2052]) {
  f32x4 v0, v1, v2, v3, v4, v5, v6, v7;
  const float* s = src + 4 * tid;
  ld8_cv(s, s + 2048, s + 4096, s + 6144, s + 8192, s + 10240, s + 12288, s + 14336,
         v0, v1, v2, v3, v4, v5, v6, v7);
  const int bb = tid >> 8, k4 = (tid & 255) * 4;
  *(f32x4*)&xls[bb + 0][dstoff + k4] = v0;
  *(f32x4*)&xls[bb + 2][dstoff + k4] = v1;
  *(f32x4*)&xls[bb + 4][dstoff + k4] = v2;
  *(f32x4*)&xls[bb + 6][dstoff + k4] = v3;
  *(f32x4*)&xls[bb + 8][dstoff + k4] = v4;
  *(f32x4*)&xls[bb + 10][dstoff + k4] = v5;
  *(f32x4*)&xls[bb + 12][dstoff + k4] = v6;
  *(f32x4*)&xls[bb + 14][dstoff + k4] = v7;
}

// Same staging but PLAIN cached loads (written-once-then-read data, e.g. x1[t]).
__device__ __forceinline__ void stage64k_pl(const float* src, int dstoff, int tid,
                                            float xls[16][2052]) {
  const float* s = src + 4 * tid;
  f32x4 v0 = *(const f32x4*)(s);
  f32x4 v1 = *(const f32x4*)(s + 2048);
  f32x4 v2 = *(const f32x4*)(s + 4096);
  f32x4 v3 = *(const f32x4*)(s + 6144);
  f32x4 v4 = *(const f32x4*)(s + 8192);
  f32x4 v5 = *(const f32x4*)(s + 10240);
  f32x4 v6 = *(const f32x4*)(s + 12288);
  f32x4 v7 = *(const f32x4*)(s + 14336);
  const int bb = tid >> 8, k4 = (tid & 255) * 4;
  *(f32x4*)&xls[bb + 0][dstoff + k4] = v0;
  *(f32x4*)&xls[bb + 2][dstoff + k4] = v1;
  *(f32x4*)&xls[bb + 4][dstoff + k4] = v2;
  *(f32x4*)&xls[bb + 6][dstoff + k4] = v3;
  *(f32x4*)&xls[bb + 8][dstoff + k4] = v4;
  *(f32x4*)&xls[bb + 10][dstoff + k4] = v5;
  *(f32x4*)&xls[bb + 12][dstoff + k4] = v6;
  *(f32x4*)&xls[bb + 14][dstoff + k4] = v7;
}

// Flat one-hop pure-asm barrier: block's wave0 publishes flag, polls all 256.
__device__ __forceinline__ void gsyncf(unsigned step, unsigned* bar) {
  __syncthreads();
  const int tid = threadIdx.x;
  if (tid == 0) flag_store(bar + 16 + blockIdx.x * 16, step);
  if (tid < 64) {
    const unsigned* base = bar + 16 + tid * 64;  // 4 flags per lane
    for (;;) {
      unsigned a, b, c, d;
      ld4_flags(base, a, b, c, d);
      bool mine = (a >= step) & (b >= step) & (c >= step) & (d >= step);
      if (__all(mine)) break;
      __builtin_amdgcn_s_sleep(1);
    }
    asm volatile("" ::: "memory");
  }
  __syncthreads();
}

__device__ __forceinline__ void dot4(float& a, float4 wv, float4 xv) {
  a = fmaf(wv.x, xv.x, a);
  a = fmaf(wv.y, xv.y, a);
  a = fmaf(wv.z, xv.z, a);
  a = fmaf(wv.w, xv.w, a);
}

#define DECL_ACC                                                        \
  float acc00 = 0.f, acc01 = 0.f, acc02 = 0.f, acc03 = 0.f,             \
        acc10 = 0.f, acc11 = 0.f, acc12 = 0.f, acc13 = 0.f,             \
        acc20 = 0.f, acc21 = 0.f, acc22 = 0.f, acc23 = 0.f,             \
        acc30 = 0.f, acc31 = 0.f, acc32 = 0.f, acc33 = 0.f;

// fp32-weight K-step (INIT ctx projection)
#define KSTEP(p0, p1, p2, p3, K4)                                       \
  {                                                                     \
    const float4 xv0 = *(const float4*)&xls[bq4][(K4)];                 \
    const float4 xv1 = *(const float4*)&xls[bq4 + 1][(K4)];             \
    const float4 xv2 = *(const float4*)&xls[bq4 + 2][(K4)];             \
    const float4 xv3 = *(const float4*)&xls[bq4 + 3][(K4)];             \
    float4 wv;                                                          \
    wv = *(const float4*)(p0);                                          \
    dot4(acc00, wv, xv0); dot4(acc01, wv, xv1);                         \
    dot4(acc02, wv, xv2); dot4(acc03, wv, xv3);                         \
    wv = *(const float4*)(p1);                                          \
    dot4(acc10, wv, xv0); dot4(acc11, wv, xv1);                         \
    dot4(acc12, wv, xv2); dot4(acc13, wv, xv3);                         \
    wv = *(const float4*)(p2);                                          \
    dot4(acc20, wv, xv0); dot4(acc21, wv, xv1);                         \
    dot4(acc22, wv, xv2); dot4(acc23, wv, xv3);                         \
    wv = *(const float4*)(p3);                                          \
    dot4(acc30, wv, xv0); dot4(acc31, wv, xv1);                         \
    dot4(acc32, wv, xv2); dot4(acc33, wv, xv3);                         \
  }

// bf16-weight double K-step (see R6): x chunks [XK,XK+256), weight k at WK.
#define KSTEPB(q0, q1, q2, q3, XK, WK)                                  \
  {                                                                     \
    const int xk = (XK) + kc * 4;                                       \
    const int wk = (WK) + kc * 4;                                       \
    const float4 xa0 = *(const float4*)&xls[bq4][xk];                   \
    const float4 xa1 = *(const float4*)&xls[bq4 + 1][xk];               \
    const float4 xa2 = *(const float4*)&xls[bq4 + 2][xk];               \
    const float4 xa3 = *(const float4*)&xls[bq4 + 3][xk];               \
    const float4 xb0 = *(const float4*)&xls[bq4][xk + 128];             \
    const float4 xb1 = *(const float4*)&xls[bq4 + 1][xk + 128];         \
    const float4 xb2 = *(const float4*)&xls[bq4 + 2][xk + 128];         \
    const float4 xb3 = *(const float4*)&xls[bq4 + 3][xk + 128];         \
    uint2 ua, ub; float4 wv;                                            \
    ua = *(const uint2*)((q0) + wk); ub = *(const uint2*)((q0) + wk + 128); \
    wv = bf2f(ua);                                                      \
    dot4(acc00, wv, xa0); dot4(acc01, wv, xa1);                         \
    dot4(acc02, wv, xa2); dot4(acc03, wv, xa3);                         \
    wv = bf2f(ub);                                                      \
    dot4(acc00, wv, xb0); dot4(acc01, wv, xb1);                         \
    dot4(acc02, wv, xb2); dot4(acc03, wv, xb3);                         \
    ua = *(const uint2*)((q1) + wk); ub = *(const uint2*)((q1) + wk + 128); \
    wv = bf2f(ua);                                                      \
    dot4(acc10, wv, xa0); dot4(acc11, wv, xa1);                         \
    dot4(acc12, wv, xa2); dot4(acc13, wv, xa3);                         \
    wv = bf2f(ub);                                                      \
    dot4(acc10, wv, xb0); dot4(acc11, wv, xb1);                         \
    dot4(acc12, wv, xb2); dot4(acc13, wv, xb3);                         \
    ua = *(const uint2*)((q2) + wk); ub = *(const uint2*)((q2) + wk + 128); \
    wv = bf2f(ua);                                                      \
    dot4(acc20, wv, xa0); dot4(acc21, wv, xa1);                         \
    dot4(acc22, wv, xa2); dot4(acc23, wv, xa3);                         \
    wv = bf2f(ub);                                                      \
    dot4(acc20, wv, xb0); dot4(acc21, wv, xb1);                         \
    dot4(acc22, wv, xb2); dot4(acc23, wv, xb3);                         \
    ua = *(const uint2*)((q3) + wk); ub = *(const uint2*)((q3) + wk + 128); \
    wv = bf2f(ua);                                                      \
    dot4(acc30, wv, xa0); dot4(acc31, wv, xa1);                         \
    dot4(acc32, wv, xa2); dot4(acc33, wv, xa3);                         \
    wv = bf2f(ub);                                                      \
    dot4(acc30, wv, xb0); dot4(acc31, wv, xb1);                         \
    dot4(acc32, wv, xb2); dot4(acc33, wv, xb3);                         \
  }

#define RED5(v)                \
  {                            \
    v += __shfl_xor(v, 1);     \
    v += __shfl_xor(v, 2);     \
    v += __shfl_xor(v, 4);     \
    v += __shfl_xor(v, 8);     \
    v += __shfl_xor(v, 16);    \
  }

#define REDUCE_ALL                                                     \
  {                                                                    \
    RED5(acc00) RED5(acc01) RED5(acc02) RED5(acc03)                    \
    RED5(acc10) RED5(acc11) RED5(acc12) RED5(acc13)                    \
    RED5(acc20) RED5(acc21) RED5(acc22) RED5(acc23)                    \
    RED5(acc30) RED5(acc31) RED5(acc32) RED5(acc33)                    \
  }

#define WRITE_GLSX(G)                                                               \
  {                                                                                 \
    if (kc == 0) {                                                                  \
      G[jq][0][bq4] = acc00; G[jq][0][bq4 + 1] = acc01;                             \
      G[jq][0][bq4 + 2] = acc02; G[jq][0][bq4 + 3] = acc03;                         \
      G[jq][1][bq4] = acc10; G[jq][1][bq4 + 1] = acc11;                             \
      G[jq][1][bq4 + 2] = acc12; G[jq][1][bq4 + 3] = acc13;                         \
      G[jq][2][bq4] = acc20; G[jq][2][bq4 + 1] = acc21;                             \
      G[jq][2][bq4 + 2] = acc22; G[jq][2][bq4 + 3] = acc23;                         \
      G[jq][3][bq4] = acc30; G[jq][3][bq4 + 1] = acc31;                             \
      G[jq][3][bq4 + 2] = acc32; G[jq][3][bq4 + 3] = acc33;                         \
    }                                                                               \
  }

// fp32 -> bf16 weight conversion (per launch; ~25us for 92MB)
__global__ void prep_bf16(const float* __restrict__ src, u16* __restrict__ dst, int n8) {
  for (int i = blockIdx.x * blockDim.x + threadIdx.x; i < n8; i += gridDim.x * blockDim.x) {
    float4 a = *(const float4*)(src + (size_t)i * 8);
    float4 b = *(const float4*)(src + (size_t)i * 8 + 4);
    __align__(16) u16 r[8] = {f2bf(a.x), f2bf(a.y), f2bf(a.z), f2bf(a.w),
                              f2bf(b.x), f2bf(b.y), f2bf(b.z), f2bf(b.w)};
    *(uint4*)(dst + (size_t)i * 8) = *(uint4*)r;
  }
}

// ---------------- cross-layer pipelined persistent decoder ----------------
__global__ __launch_bounds__(512, 2) void dec_seq_pl(
    const float* __restrict__ enc_h, const float* __restrict__ enc_c,
    const int* __restrict__ tgt, const float* __restrict__ emb,
    const float* __restrict__ wih0, const float* __restrict__ bih0,
    const float* __restrict__ bhh0, const float* __restrict__ bih1,
    const float* __restrict__ bhh1,
    const u16* __restrict__ wb_ih0, const u16* __restrict__ wb_hh0,
    const u16* __restrict__ wb_ih1, const u16* __restrict__ wb_hh1,
    float* __restrict__ h0b, float* __restrict__ h1b,
    float* __restrict__ x1, u16* __restrict__ out2b,
    unsigned* bar) {
  __shared__ float xls[16][2052];
  __shared__ float glsA[4][4][16];
  __shared__ float glsB[4][4][16];

  const int tid = threadIdx.x;
  const int wgid = blockIdx.x;
  const int kc = tid & 31;
  const int combo = tid >> 5;
  const int jq = combo >> 2;
  const int bq4 = (combo & 3) * 4;
  const int w4 = wgid * 4;
  unsigned step = 0;

  const int j0 = jq * 1024 + w4;
  // fp32 rows (INIT ctx projection only)
  const float* wih0r0 = wih0 + (size_t)(j0 + 0) * 2560;
  const float* wih0r1 = wih0 + (size_t)(j0 + 1) * 2560;
  const float* wih0r2 = wih0 + (size_t)(j0 + 2) * 2560;
  const float* wih0r3 = wih0 + (size_t)(j0 + 3) * 2560;
  // bf16 rows (hot loop)
  const u16* qih0r0 = wb_ih0 + (size_t)(j0 + 0) * 2560;
  const u16* qih0r1 = wb_ih0 + (size_t)(j0 + 1) * 2560;
  const u16* qih0r2 = wb_ih0 + (size_t)(j0 + 2) * 2560;
  const u16* qih0r3 = wb_ih0 + (size_t)(j0 + 3) * 2560;
  const u16* qhh0r0 = wb_hh0 + (size_t)(j0 + 0) * 1024;
  const u16* qhh0r1 = wb_hh0 + (size_t)(j0 + 1) * 1024;
  const u16* qhh0r2 = wb_hh0 + (size_t)(j0 + 2) * 1024;
  const u16* qhh0r3 = wb_hh0 + (size_t)(j0 + 3) * 1024;
  const u16* qih1r0 = wb_ih1 + (size_t)(j0 + 0) * 1024;
  const u16* qih1r1 = wb_ih1 + (size_t)(j0 + 1) * 1024;
  const u16* qih1r2 = wb_ih1 + (size_t)(j0 + 2) * 1024;
  const u16* qih1r3 = wb_ih1 + (size_t)(j0 + 3) * 1024;
  const u16* qhh1r0 = wb_hh1 + (size_t)(j0 + 0) * 1024;
  const u16* qhh1r1 = wb_hh1 + (size_t)(j0 + 1) * 1024;
  const u16* qhh1r2 = wb_hh1 + (size_t)(j0 + 2) * 1024;
  const u16* qhh1r3 = wb_hh1 + (size_t)(j0 + 3) * 1024;

  const int gdj = tid >> 4;
  const int gb = tid & 15;
  float cpA0 = 0.f, cpA1 = 0.f, cpA2 = 0.f, cpA3 = 0.f;
  float cpB0 = 0.f, cpB1 = 0.f, cpB2 = 0.f, cpB3 = 0.f;
  float c0r = 0.f, c1r = 0.f;

  // ---------------- INIT: ctx projection (fp32) + biases + h/c ----------------
#pragma unroll
  for (int c = 0; c < 16; ++c) {
    int f4 = tid + c * 512;
    int b = f4 >> 9, kq = f4 & 511;
    const float4 v = *(const float4*)(enc_h + (kq >> 7) * 8192 + b * 512 + (kq & 127) * 4);
    *(float4*)&xls[b][kq * 4] = v;
  }
  __syncthreads();
  {
    DECL_ACC
#pragma unroll 4
    for (int i = 0; i < 16; ++i) {
      const int k4 = i * 128 + kc * 4;
      KSTEP(wih0r0 + 512 + k4, wih0r1 + 512 + k4, wih0r2 + 512 + k4, wih0r3 + 512 + k4, k4)
    }
    REDUCE_ALL
    WRITE_GLSX(glsA)
  }
  __syncthreads();
  if (tid < 64) {
    const int jp = w4 + gdj;
    cpA0 = glsA[0][gdj][gb] + bih0[jp] + bhh0[jp];
    cpA1 = glsA[1][gdj][gb] + bih0[1024 + jp] + bhh0[1024 + jp];
    cpA2 = glsA[2][gdj][gb] + bih0[2048 + jp] + bhh0[2048 + jp];
    cpA3 = glsA[3][gdj][gb] + bih0[3072 + jp] + bhh0[3072 + jp];
    cpB0 = bih1[jp] + bhh1[jp];
    cpB1 = bih1[1024 + jp] + bhh1[1024 + jp];
    cpB2 = bih1[2048 + jp] + bhh1[2048 + jp];
    cpB3 = bih1[3072 + jp] + bhh1[3072 + jp];
    const int dir = jp >> 9, e = jp & 511;
    c0r = enc_c[dir * 8192 + gb * 512 + e];
    c1r = enc_c[(2 + dir) * 8192 + gb * 512 + e];
    st_cv(h0b + gb * 1024 + jp, enc_h[dir * 8192 + gb * 512 + e]);
    st_cv(h1b + gb * 1024 + jp, enc_h[(2 + dir) * 8192 + gb * 512 + e]);
  }
  gsyncf(++step, bar);

  // ---------------- PIPELINED MAIN LOOP: 129 macro-steps, 1 barrier each ----
  // macro-step s: phase A = L0[t=s] (s<128); phase B = L1[t=s-1] (s>=1).
  int cur0 = 0, cur1 = 0;
  for (int s = 0; s < 129; ++s) {
    // ---- Phase A: LSTM layer 0 at t = s ----
    if (s < 128) {
#pragma unroll
      for (int c = 0; c < 4; ++c) {
        int f4 = tid + c * 512;
        int b = f4 >> 7, kq = f4 & 127;
        int tok = (s == 0) ? 1 : tgt[b * 128 + (s - 1)];
        const float4 v = *(const float4*)(emb + (size_t)tok * 512 + kq * 4);
        *(float4*)&xls[b][kq * 4] = v;
      }
      stage64k(h0b + cur0 * 16384, 512, tid, xls);
      __syncthreads();
      {
        DECL_ACC
        KSTEPB(qih0r0, qih0r1, qih0r2, qih0r3, 0, 0)
        KSTEPB(qih0r0, qih0r1, qih0r2, qih0r3, 256, 256)
        KSTEPB(qhh0r0, qhh0r1, qhh0r2, qhh0r3, 512, 0)
        KSTEPB(qhh0r0, qhh0r1, qhh0r2, qhh0r3, 768, 256)
        KSTEPB(qhh0r0, qhh0r1, qhh0r2, qhh0r3, 1024, 512)
        KSTEPB(qhh0r0, qhh0r1, qhh0r2, qhh0r3, 1280, 768)
        REDUCE_ALL
        WRITE_GLSX(glsA)
      }
      __syncthreads();  // glsA ready; also all xls reads of phase A done
      if (tid < 64) {
        const int jp = w4 + gdj;
        float gi = glsA[0][gdj][gb] + cpA0;
        float gf = glsA[1][gdj][gb] + cpA1;
        float gg = glsA[2][gdj][gb] + cpA2;
        float go = glsA[3][gdj][gb] + cpA3;
        c0r = sigf(gf) * c0r + sigf(gi) * tanh_(gg);
        float h = sigf(go) * tanh_(c0r);
        st_cv(h0b + (cur0 ^ 1) * 16384 + gb * 1024 + jp, h);
        st_cv(x1 + s * 16384 + gb * 1024 + jp, h);
      }
      cur0 ^= 1;
    }

    // ---- Phase B: LSTM layer 1 at t = s-1 ----
    if (s >= 1) {
      stage64k_pl(x1 + (s - 1) * 16384, 0, tid, xls);  // written once, cached
      stage64k(h1b + cur1 * 16384, 1024, tid, xls);    // rewritten, bypass
      __syncthreads();
      {
        DECL_ACC
        KSTEPB(qih1r0, qih1r1, qih1r2, qih1r3, 0, 0)
        KSTEPB(qih1r0, qih1r1, qih1r2, qih1r3, 256, 256)
        KSTEPB(qih1r0, qih1r1, qih1r2, qih1r3, 512, 512)
        KSTEPB(qih1r0, qih1r1, qih1r2, qih1r3, 768, 768)
        KSTEPB(qhh1r0, qhh1r1, qhh1r2, qhh1r3, 1024, 0)
        KSTEPB(qhh1r0, qhh1r1, qhh1r2, qhh1r3, 1280, 256)
        KSTEPB(qhh1r0, qhh1r1, qhh1r2, qhh1r3, 1536, 512)
        KSTEPB(qhh1r0, qhh1r1, qhh1r2, qhh1r3, 1792, 768)
        REDUCE_ALL
        WRITE_GLSX(glsB)
      }
      __syncthreads();
      if (tid < 64) {
        const int jp = w4 + gdj;
        float gi = glsB[0][gdj][gb] + cpB0;
        float gf = glsB[1][gdj][gb] + cpB1;
        float gg = glsB[2][gdj][gb] + cpB2;
        float go = glsB[3][gdj][gb] + cpB3;
        c1r = sigf(gf) * c1r + sigf(gi) * tanh_(gg);
        float h = sigf(go) * tanh_(c1r);
        st_cv(h1b + (cur1 ^ 1) * 16384 + gb * 1024 + jp, h);
        out2b[((s - 1) * 16 + gb) * 1024 + jp] = f2bf(tanh_(h));
      }
      cur1 ^= 1;
    }

    gsyncf(++step, bar);  // single grid barrier per macro-step
  }
}

// logits GEMM: A bf16 [2048][1024]; B fp32 [32000][1024] (cvt per tile); C fp32.
__global__ __launch_bounds__(256, 2) void fc_gemm_mfma(
    const u16* __restrict__ A, const float* __restrict__ Bw,
    const float* __restrict__ bias, float* __restrict__ C) {
  __shared__ __align__(16) u16 Al[128][40];
  __shared__ __align__(16) u16 Bl[128][40];

  const int tid = threadIdx.x;
  const int m0 = blockIdx.x * 128;
  const int n0 = blockIdx.y * 128;
  const int wave = tid >> 6;
  const int lane = tid & 63;
  const int wm = (wave & 1) * 64;
  const int wn = (wave >> 1) * 64;
  const int fr = lane & 15;
  const int ks = lane >> 4;

  const int srow = tid >> 1;
  const int sh16 = (tid & 1) * 16;

  const u16* Ag = A + (size_t)(m0 + srow) * 1024 + sh16;
  const float* Bg = Bw + (size_t)(n0 + srow) * 1024 + sh16;

  f32x4 acc[4][4] = {};

  for (int k0 = 0; k0 < 1024; k0 += 32) {
    uint4 a0 = *(const uint4*)(Ag + k0);
    uint4 a1 = *(const uint4*)(Ag + k0 + 8);
    float bfv[16];
    *(float4*)&bfv[0] = *(const float4*)(Bg + k0);
    *(float4*)&bfv[4] = *(const float4*)(Bg + k0 + 4);
    *(float4*)&bfv[8] = *(const float4*)(Bg + k0 + 8);
    *(float4*)&bfv[12] = *(const float4*)(Bg + k0 + 12);
    u16 bu[16];
#pragma unroll
    for (int u = 0; u < 16; ++u) bu[u] = f2bf(bfv[u]);

    __syncthreads();
    *(uint4*)&Al[srow][sh16] = a0;
    *(uint4*)&Al[srow][sh16 + 8] = a1;
    *(uint4*)&Bl[srow][sh16] = *(uint4*)&bu[0];
    *(uint4*)&Bl[srow][sh16 + 8] = *(uint4*)&bu[8];
    __syncthreads();

    bf16x8 af[4], bf[4];
#pragma unroll
    for (int i = 0; i < 4; ++i) af[i] = *(const bf16x8*)&Al[wm + i * 16 + fr][ks * 8];
#pragma unroll
    for (int j = 0; j < 4; ++j) bf[j] = *(const bf16x8*)&Bl[wn + j * 16 + fr][ks * 8];
#pragma unroll
    for (int i = 0; i < 4; ++i)
#pragma unroll
      for (int j = 0; j < 4; ++j)
        acc[i][j] = __builtin_amdgcn_mfma_f32_16x16x32_bf16(af[i], bf[j], acc[i][j], 0, 0, 0);
  }

  float bj[4];
#pragma unroll
  for (int j = 0; j < 4; ++j) bj[j] = bias[n0 + wn + j * 16 + fr];

  const int mrb = (lane >> 4) * 4;
#pragma unroll
  for (int i = 0; i < 4; ++i) {
#pragma unroll
    for (int r = 0; r < 4; ++r) {
      const int m = m0 + wm + i * 16 + mrb + r;
      float* dst = C + ((size_t)(m & 15) * 128 + (m >> 4)) * 32000;
#pragma unroll
      for (int j = 0; j < 4; ++j) {
        dst[n0 + wn + j * 16 + fr] = acc[i][j][r] + bj[j];
      }
    }
  }
}

extern "C" void kernel_launch(void* const* d_in, const int* in_sizes, int n_in,
                              void* d_out, int out_size, void* d_ws, size_t ws_size,
                              hipStream_t stream) {
  const float* enc_h = (const float*)d_in[0];
  const float* enc_c = (const float*)d_in[1];
  const int* tgt = (const int*)d_in[2];
  const float* emb = (const float*)d_in[3];
  const float* wih0 = (const float*)d_in[4];
  const float* whh0 = (const float*)d_in[5];
  const float* bih0 = (const float*)d_in[6];
  const float* bhh0 = (const float*)d_in[7];
  const float* wih1 = (const float*)d_in[8];
  const float* whh1 = (const float*)d_in[9];
  const float* bih1 = (const float*)d_in[10];
  const float* bhh1 = (const float*)d_in[11];
  const float* fcw = (const float*)d_in[12];
  const float* fcb = (const float*)d_in[13];
  float* logits = (float*)d_out;

  unsigned* bar = (unsigned*)d_ws;  // 32 KB barrier region
  hipMemsetAsync(d_ws, 0, 64 + 256 * 64, stream);

  u16* wb_ih0 = (u16*)((char*)d_ws + 32768);
  u16* wb_hh0 = wb_ih0 + 10485760;   // 4096*2560
  u16* wb_ih1 = wb_hh0 + 4194304;    // 4096*1024
  u16* wb_hh1 = wb_ih1 + 4194304;
  float* h0b = (float*)(wb_hh1 + 4194304);
  float* h1b = h0b + 32768;
  float* x1 = h1b + 32768;
  u16* out2b = (u16*)(x1 + 2097152);

  prep_bf16<<<2048, 256, 0, stream>>>(wih0, wb_ih0, 1310720);
  prep_bf16<<<2048, 256, 0, stream>>>(whh0, wb_hh0, 524288);
  prep_bf16<<<2048, 256, 0, stream>>>(wih1, wb_ih1, 524288);
  prep_bf16<<<2048, 256, 0, stream>>>(whh1, wb_hh1, 524288);
  dec_seq_pl<<<NBLK, 512, 0, stream>>>(enc_h, enc_c, tgt, emb, wih0, bih0, bhh0,
                                       bih1, bhh1, wb_ih0, wb_hh0, wb_ih1, wb_hh1,
                                       h0b, h1b, x1, out2b, bar);
  fc_gemm_mfma<<<dim3(16, 250), 256, 0, stream>>>(out2b, fcw, fcb, logits);
}

// Round 8
// 3107.278 us; speedup vs baseline: 1.1477x; 1.0173x over previous
//
#include <hip/hip_runtime.h>

// Decoder: B=16, T=128, V=32000, E=512, H=1024 (2 LSTM layers), CTX=2048.
// dec_seq_pl: persistent 256 blocks x 512 threads, bf16 weights, cross-layer
//   pipelined (129 grid barriers). KEY (R8): h0/h1 live in WRITE-ONCE RINGS
//   (one slab per step) read with PLAIN CACHED loads -> 32 blocks/XCD share
//   L2 lines instead of each bypass-fetching 64KB from MALL (was 16-48MB/step
//   broadcast = the ~10us/step floor). Write side stays sc0/sc1 write-through;
//   ring addresses are written exactly once per launch so no stale-line hazard
//   (x1 ring validated this pattern in R5-R7). bf16 w_ih0 keeps only the emb
//   512 cols -> hot weights 29.4MB, 3.67MB/XCD: fits L2 even fused.
// fc_gemm_mfma: bf16 MFMA GEMM -> [16][128][32000] logits (~125us).

#define NBLK 256

typedef float f32x4 __attribute__((ext_vector_type(4)));
typedef __bf16 bf16x8 __attribute__((ext_vector_type(8)));
typedef unsigned short u16;

__device__ __forceinline__ float sigf(float x) { return 1.0f / (1.0f + __expf(-x)); }
__device__ __forceinline__ float tanh_(float x) {
  x = fminf(15.0f, fmaxf(-15.0f, x));
  float e = __expf(2.0f * x);
  return (e - 1.0f) / (e + 1.0f);
}

__device__ __forceinline__ u16 f2bf(float f) {
  __bf16 h = (__bf16)f;  // RNE
  return __builtin_bit_cast(u16, h);
}

// unpack 4 bf16 (packed low->high k order) to float4
__device__ __forceinline__ float4 bf2f(uint2 u) {
  float4 r;
  r.x = __builtin_bit_cast(float, u.x << 16);
  r.y = __builtin_bit_cast(float, u.x & 0xffff0000u);
  r.z = __builtin_bit_cast(float, u.y << 16);
  r.w = __builtin_bit_cast(float, u.y & 0xffff0000u);
  return r;
}

// Coherent (write-through) scalar store.
__device__ __forceinline__ void st_cv(float* p, float v) {
  asm volatile("global_store_dword %0, %1, off sc0 sc1" :: "v"(p), "v"(v) : "memory");
}

// Flag publish: drain own data stores, then plain sc0/sc1 flag store.
__device__ __forceinline__ void flag_store(unsigned* p, unsigned v) {
  asm volatile(
      "s_waitcnt vmcnt(0)\n\t"
      "global_store_dword %0, %1, off sc0 sc1"
      :: "v"(p), "v"(v) : "memory");
}

// 4 bypass flag loads in flight, one waitcnt (no atomic lowering -> no buffer_inv).
__device__ __forceinline__ void ld4_flags(const unsigned* p, unsigned& a, unsigned& b,
                                          unsigned& c, unsigned& d) {
  asm volatile(
      "global_load_dword %0, %4, off sc0 sc1\n\t"
      "global_load_dword %1, %5, off sc0 sc1\n\t"
      "global_load_dword %2, %6, off sc0 sc1\n\t"
      "global_load_dword %3, %7, off sc0 sc1\n\t"
      "s_waitcnt vmcnt(0)"
      : "=&v"(a), "=&v"(b), "=&v"(c), "=&v"(d)
      : "v"(p), "v"(p + 16), "v"(p + 32), "v"(p + 48)
      : "memory");
}

// Stage a 16x1024 float slab (64KB) src -> xls[0..15][dstoff..+1023].
// PLAIN cached loads: slab is written exactly once per launch (ring), so
// cached reads are safe and 31/32 blocks per XCD hit L2.
__device__ __forceinline__ void stage64k_pl(const float* src, int dstoff, int tid,
                                            float xls[16][2052]) {
  const float* s = src + 4 * tid;
  f32x4 v0 = *(const f32x4*)(s);
  f32x4 v1 = *(const f32x4*)(s + 2048);
  f32x4 v2 = *(const f32x4*)(s + 4096);
  f32x4 v3 = *(const f32x4*)(s + 6144);
  f32x4 v4 = *(const f32x4*)(s + 8192);
  f32x4 v5 = *(const f32x4*)(s + 10240);
  f32x4 v6 = *(const f32x4*)(s + 12288);
  f32x4 v7 = *(const f32x4*)(s + 14336);
  const int bb = tid >> 8, k4 = (tid & 255) * 4;
  *(f32x4*)&xls[bb + 0][dstoff + k4] = v0;
  *(f32x4*)&xls[bb + 2][dstoff + k4] = v1;
  *(f32x4*)&xls[bb + 4][dstoff + k4] = v2;
  *(f32x4*)&xls[bb + 6][dstoff + k4] = v3;
  *(f32x4*)&xls[bb + 8][dstoff + k4] = v4;
  *(f32x4*)&xls[bb + 10][dstoff + k4] = v5;
  *(f32x4*)&xls[bb + 12][dstoff + k4] = v6;
  *(f32x4*)&xls[bb + 14][dstoff + k4] = v7;
}

// Split-destination stage for the h1 slab: k<512 -> cols [0..511],
// k>=512 -> cols [1536..2047] (keeps x1 slab at cols 512..1535 intact).
__device__ __forceinline__ void stage64k_split(const float* src, int tid,
                                               float xls[16][2052]) {
  const float* s = src + 4 * tid;
  f32x4 v0 = *(const f32x4*)(s);
  f32x4 v1 = *(const f32x4*)(s + 2048);
  f32x4 v2 = *(const f32x4*)(s + 4096);
  f32x4 v3 = *(const f32x4*)(s + 6144);
  f32x4 v4 = *(const f32x4*)(s + 8192);
  f32x4 v5 = *(const f32x4*)(s + 10240);
  f32x4 v6 = *(const f32x4*)(s + 12288);
  f32x4 v7 = *(const f32x4*)(s + 14336);
  const int bb = tid >> 8, k4 = (tid & 255) * 4;
  const int col = (k4 < 512) ? k4 : k4 + 1024;
  *(f32x4*)&xls[bb + 0][col] = v0;
  *(f32x4*)&xls[bb + 2][col] = v1;
  *(f32x4*)&xls[bb + 4][col] = v2;
  *(f32x4*)&xls[bb + 6][col] = v3;
  *(f32x4*)&xls[bb + 8][col] = v4;
  *(f32x4*)&xls[bb + 10][col] = v5;
  *(f32x4*)&xls[bb + 12][col] = v6;
  *(f32x4*)&xls[bb + 14][col] = v7;
}

// Flat one-hop pure-asm barrier: block's wave0 publishes flag, polls all 256.
__device__ __forceinline__ void gsyncf(unsigned step, unsigned* bar) {
  __syncthreads();
  const int tid = threadIdx.x;
  if (tid == 0) flag_store(bar + 16 + blockIdx.x * 16, step);
  if (tid < 64) {
    const unsigned* base = bar + 16 + tid * 64;  // 4 flags per lane
    for (;;) {
      unsigned a, b, c, d;
      ld4_flags(base, a, b, c, d);
      bool mine = (a >= step) & (b >= step) & (c >= step) & (d >= step);
      if (__all(mine)) break;
      __builtin_amdgcn_s_sleep(1);
    }
    asm volatile("" ::: "memory");
  }
  __syncthreads();
}

__device__ __forceinline__ void dot4(float& a, float4 wv, float4 xv) {
  a = fmaf(wv.x, xv.x, a);
  a = fmaf(wv.y, xv.y, a);
  a = fmaf(wv.z, xv.z, a);
  a = fmaf(wv.w, xv.w, a);
}

#define DECL_ACC                                                        \
  float acc00 = 0.f, acc01 = 0.f, acc02 = 0.f, acc03 = 0.f,             \
        acc10 = 0.f, acc11 = 0.f, acc12 = 0.f, acc13 = 0.f,             \
        acc20 = 0.f, acc21 = 0.f, acc22 = 0.f, acc23 = 0.f,             \
        acc30 = 0.f, acc31 = 0.f, acc32 = 0.f, acc33 = 0.f;

// fp32-weight K-step (INIT ctx projection only)
#define KSTEP(p0, p1, p2, p3, K4)                                       \
  {                                                                     \
    const float4 xv0 = *(const float4*)&xls[bq4][(K4)];                 \
    const float4 xv1 = *(const float4*)&xls[bq4 + 1][(K4)];             \
    const float4 xv2 = *(const float4*)&xls[bq4 + 2][(K4)];             \
    const float4 xv3 = *(const float4*)&xls[bq4 + 3][(K4)];             \
    float4 wv;                                                          \
    wv = *(const float4*)(p0);                                          \
    dot4(acc00, wv, xv0); dot4(acc01, wv, xv1);                         \
    dot4(acc02, wv, xv2); dot4(acc03, wv, xv3);                         \
    wv = *(const float4*)(p1);                                          \
    dot4(acc10, wv, xv0); dot4(acc11, wv, xv1);                         \
    dot4(acc12, wv, xv2); dot4(acc13, wv, xv3);                         \
    wv = *(const float4*)(p2);                                          \
    dot4(acc20, wv, xv0); dot4(acc21, wv, xv1);                         \
    dot4(acc22, wv, xv2); dot4(acc23, wv, xv3);                         \
    wv = *(const float4*)(p3);                                          \
    dot4(acc30, wv, xv0); dot4(acc31, wv, xv1);                         \
    dot4(acc32, wv, xv2); dot4(acc33, wv, xv3);                         \
  }

// bf16-weight double K-step: x chunks [XK,XK+256), weight k at [WK,WK+256).
#define KSTEPB(q0, q1, q2, q3, XK, WK)                                  \
  {                                                                     \
    const int xk = (XK) + kc * 4;                                       \
    const int wk = (WK) + kc * 4;                                       \
    const float4 xa0 = *(const float4*)&xls[bq4][xk];                   \
    const float4 xa1 = *(const float4*)&xls[bq4 + 1][xk];               \
    const float4 xa2 = *(const float4*)&xls[bq4 + 2][xk];               \
    const float4 xa3 = *(const float4*)&xls[bq4 + 3][xk];               \
    const float4 xb0 = *(const float4*)&xls[bq4][xk + 128];             \
    const float4 xb1 = *(const float4*)&xls[bq4 + 1][xk + 128];         \
    const float4 xb2 = *(const float4*)&xls[bq4 + 2][xk + 128];         \
    const float4 xb3 = *(const float4*)&xls[bq4 + 3][xk + 128];         \
    uint2 ua, ub; float4 wv;                                            \
    ua = *(const uint2*)((q0) + wk); ub = *(const uint2*)((q0) + wk + 128); \
    wv = bf2f(ua);                                                      \
    dot4(acc00, wv, xa0); dot4(acc01, wv, xa1);                         \
    dot4(acc02, wv, xa2); dot4(acc03, wv, xa3);                         \
    wv = bf2f(ub);                                                      \
    dot4(acc00, wv, xb0); dot4(acc01, wv, xb1);                         \
    dot4(acc02, wv, xb2); dot4(acc03, wv, xb3);                         \
    ua = *(const uint2*)((q1) + wk); ub = *(const uint2*)((q1) + wk + 128); \
    wv = bf2f(ua);                                                      \
    dot4(acc10, wv, xa0); dot4(acc11, wv, xa1);                         \
    dot4(acc12, wv, xa2); dot4(acc13, wv, xa3);                         \
    wv = bf2f(ub);                                                      \
    dot4(acc10, wv, xb0); dot4(acc11, wv, xb1);                         \
    dot4(acc12, wv, xb2); dot4(acc13, wv, xb3);                         \
    ua = *(const uint2*)((q2) + wk); ub = *(const uint2*)((q2) + wk + 128); \
    wv = bf2f(ua);                                                      \
    dot4(acc20, wv, xa0); dot4(acc21, wv, xa1);                         \
    dot4(acc22, wv, xa2); dot4(acc23, wv, xa3);                         \
    wv = bf2f(ub);                                                      \
    dot4(acc20, wv, xb0); dot4(acc21, wv, xb1);                         \
    dot4(acc22, wv, xb2); dot4(acc23, wv, xb3);                         \
    ua = *(const uint2*)((q3) + wk); ub = *(const uint2*)((q3) + wk + 128); \
    wv = bf2f(ua);                                                      \
    dot4(acc30, wv, xa0); dot4(acc31, wv, xa1);                         \
    dot4(acc32, wv, xa2); dot4(acc33, wv, xa3);                         \
    wv = bf2f(ub);                                                      \
    dot4(acc30, wv, xb0); dot4(acc31, wv, xb1);                         \
    dot4(acc32, wv, xb2); dot4(acc33, wv, xb3);                         \
  }

#define RED5(v)                \
  {                            \
    v += __shfl_xor(v, 1);     \
    v += __shfl_xor(v, 2);     \
    v += __shfl_xor(v, 4);     \
    v += __shfl_xor(v, 8);     \
    v += __shfl_xor(v, 16);    \
  }

#define REDUCE_ALL                                                     \
  {                                                                    \
    RED5(acc00) RED5(acc01) RED5(acc02) RED5(acc03)                    \
    RED5(acc10) RED5(acc11) RED5(acc12) RED5(acc13)                    \
    RED5(acc20) RED5(acc21) RED5(acc22) RED5(acc23)                    \
    RED5(acc30) RED5(acc31) RED5(acc32) RED5(acc33)                    \
  }

#define WRITE_GLSX(G)                                                               \
  {                                                                                 \
    if (kc == 0) {                                                                  \
      G[jq][0][bq4] = acc00; G[jq][0][bq4 + 1] = acc01;                             \
      G[jq][0][bq4 + 2] = acc02; G[jq][0][bq4 + 3] = acc03;                         \
      G[jq][1][bq4] = acc10; G[jq][1][bq4 + 1] = acc11;                             \
      G[jq][1][bq4 + 2] = acc12; G[jq][1][bq4 + 3] = acc13;                         \
      G[jq][2][bq4] = acc20; G[jq][2][bq4 + 1] = acc21;                             \
      G[jq][2][bq4 + 2] = acc22; G[jq][2][bq4 + 3] = acc23;                         \
      G[jq][3][bq4] = acc30; G[jq][3][bq4 + 1] = acc31;                             \
      G[jq][3][bq4 + 2] = acc32; G[jq][3][bq4 + 3] = acc33;                         \
    }                                                                               \
  }

// fp32 -> bf16 weight conversion (contiguous)
__global__ void prep_bf16(const float* __restrict__ src, u16* __restrict__ dst, int n8) {
  for (int i = blockIdx.x * blockDim.x + threadIdx.x; i < n8; i += gridDim.x * blockDim.x) {
    float4 a = *(const float4*)(src + (size_t)i * 8);
    float4 b = *(const float4*)(src + (size_t)i * 8 + 4);
    __align__(16) u16 r[8] = {f2bf(a.x), f2bf(a.y), f2bf(a.z), f2bf(a.w),
                              f2bf(b.x), f2bf(b.y), f2bf(b.z), f2bf(b.w)};
    *(uint4*)(dst + (size_t)i * 8) = *(uint4*)r;
  }
}

// fp32 [4096][2560] -> bf16 [4096][512] (first 512 cols = emb part of w_ih0)
__global__ void prep_bf16_s(const float* __restrict__ src, u16* __restrict__ dst, int n8) {
  for (int i = blockIdx.x * blockDim.x + threadIdx.x; i < n8; i += gridDim.x * blockDim.x) {
    const int r = i >> 6, c = (i & 63) * 8;
    const float* s = src + (size_t)r * 2560 + c;
    float4 a = *(const float4*)s;
    float4 b = *(const float4*)(s + 4);
    __align__(16) u16 rr[8] = {f2bf(a.x), f2bf(a.y), f2bf(a.z), f2bf(a.w),
                               f2bf(b.x), f2bf(b.y), f2bf(b.z), f2bf(b.w)};
    *(uint4*)(dst + (size_t)r * 512 + c) = *(uint4*)rr;
  }
}

// ---------------- cross-layer pipelined persistent decoder ----------------
// Rings: x1r slot(t)=t+1 holds h0/x1 at step t (slot 0 = initial h0);
//        h1r slot(t)=t+1 holds h1 at step t (slot 0 = initial h1).
__global__ __launch_bounds__(512, 2) void dec_seq_pl(
    const float* __restrict__ enc_h, const float* __restrict__ enc_c,
    const int* __restrict__ tgt, const float* __restrict__ emb,
    const float* __restrict__ wih0, const float* __restrict__ bih0,
    const float* __restrict__ bhh0, const float* __restrict__ bih1,
    const float* __restrict__ bhh1,
    const u16* __restrict__ wb_e, const u16* __restrict__ wb_hh0,
    const u16* __restrict__ wb_ih1, const u16* __restrict__ wb_hh1,
    float* __restrict__ x1r, float* __restrict__ h1r,
    u16* __restrict__ out2b, unsigned* bar) {
  __shared__ float xls[16][2052];
  __shared__ float glsA[4][4][16];
  __shared__ float glsB[4][4][16];

  const int tid = threadIdx.x;
  const int wgid = blockIdx.x;
  const int kc = tid & 31;
  const int combo = tid >> 5;
  const int jq = combo >> 2;
  const int bq4 = (combo & 3) * 4;
  const int w4 = wgid * 4;
  unsigned step = 0;

  const int j0 = jq * 1024 + w4;
  // fp32 rows (INIT ctx projection only)
  const float* wih0r0 = wih0 + (size_t)(j0 + 0) * 2560;
  const float* wih0r1 = wih0 + (size_t)(j0 + 1) * 2560;
  const float* wih0r2 = wih0 + (size_t)(j0 + 2) * 2560;
  const float* wih0r3 = wih0 + (size_t)(j0 + 3) * 2560;
  // bf16 rows (hot loop)
  const u16* qe0 = wb_e + (size_t)(j0 + 0) * 512;
  const u16* qe1 = wb_e + (size_t)(j0 + 1) * 512;
  const u16* qe2 = wb_e + (size_t)(j0 + 2) * 512;
  const u16* qe3 = wb_e + (size_t)(j0 + 3) * 512;
  const u16* qhh0r0 = wb_hh0 + (size_t)(j0 + 0) * 1024;
  const u16* qhh0r1 = wb_hh0 + (size_t)(j0 + 1) * 1024;
  const u16* qhh0r2 = wb_hh0 + (size_t)(j0 + 2) * 1024;
  const u16* qhh0r3 = wb_hh0 + (size_t)(j0 + 3) * 1024;
  const u16* qih1r0 = wb_ih1 + (size_t)(j0 + 0) * 1024;
  const u16* qih1r1 = wb_ih1 + (size_t)(j0 + 1) * 1024;
  const u16* qih1r2 = wb_ih1 + (size_t)(j0 + 2) * 1024;
  const u16* qih1r3 = wb_ih1 + (size_t)(j0 + 3) * 1024;
  const u16* qhh1r0 = wb_hh1 + (size_t)(j0 + 0) * 1024;
  const u16* qhh1r1 = wb_hh1 + (size_t)(j0 + 1) * 1024;
  const u16* qhh1r2 = wb_hh1 + (size_t)(j0 + 2) * 1024;
  const u16* qhh1r3 = wb_hh1 + (size_t)(j0 + 3) * 1024;

  const int gdj = tid >> 4;
  const int gb = tid & 15;
  float cpA0 = 0.f, cpA1 = 0.f, cpA2 = 0.f, cpA3 = 0.f;
  float cpB0 = 0.f, cpB1 = 0.f, cpB2 = 0.f, cpB3 = 0.f;
  float c0r = 0.f, c1r = 0.f;

  // ---------------- INIT: ctx projection (fp32) + biases + h/c ----------------
#pragma unroll
  for (int c = 0; c < 16; ++c) {
    int f4 = tid + c * 512;
    int b = f4 >> 9, kq = f4 & 511;
    const float4 v = *(const float4*)(enc_h + (kq >> 7) * 8192 + b * 512 + (kq & 127) * 4);
    *(float4*)&xls[b][kq * 4] = v;
  }
  __syncthreads();
  {
    DECL_ACC
#pragma unroll 4
    for (int i = 0; i < 16; ++i) {
      const int k4 = i * 128 + kc * 4;
      KSTEP(wih0r0 + 512 + k4, wih0r1 + 512 + k4, wih0r2 + 512 + k4, wih0r3 + 512 + k4, k4)
    }
    REDUCE_ALL
    WRITE_GLSX(glsA)
  }
  __syncthreads();
  if (tid < 64) {
    const int jp = w4 + gdj;
    cpA0 = glsA[0][gdj][gb] + bih0[jp] + bhh0[jp];
    cpA1 = glsA[1][gdj][gb] + bih0[1024 + jp] + bhh0[1024 + jp];
    cpA2 = glsA[2][gdj][gb] + bih0[2048 + jp] + bhh0[2048 + jp];
    cpA3 = glsA[3][gdj][gb] + bih0[3072 + jp] + bhh0[3072 + jp];
    cpB0 = bih1[jp] + bhh1[jp];
    cpB1 = bih1[1024 + jp] + bhh1[1024 + jp];
    cpB2 = bih1[2048 + jp] + bhh1[2048 + jp];
    cpB3 = bih1[3072 + jp] + bhh1[3072 + jp];
    const int dir = jp >> 9, e = jp & 511;
    c0r = enc_c[dir * 8192 + gb * 512 + e];
    c1r = enc_c[(2 + dir) * 8192 + gb * 512 + e];
    st_cv(x1r + gb * 1024 + jp, enc_h[dir * 8192 + gb * 512 + e]);        // slot 0
    st_cv(h1r + gb * 1024 + jp, enc_h[(2 + dir) * 8192 + gb * 512 + e]);  // slot 0
  }
  gsyncf(++step, bar);

  // ---------------- PIPELINED MAIN LOOP: 129 macro-steps, 1 barrier each ----
  // macro-step s: phase A = L0[t=s] (s<128); phase B = L1[t=s-1] (s>=1).
  for (int s = 0; s < 129; ++s) {
    // ---- Phase A: LSTM layer 0 at t = s ----
    if (s < 128) {
#pragma unroll
      for (int c = 0; c < 4; ++c) {
        int f4 = tid + c * 512;
        int b = f4 >> 7, kq = f4 & 127;
        int tok = (s == 0) ? 1 : tgt[b * 128 + (s - 1)];
        const float4 v = *(const float4*)(emb + (size_t)tok * 512 + kq * 4);
        *(float4*)&xls[b][kq * 4] = v;
      }
      stage64k_pl(x1r + (size_t)s * 16384, 512, tid, xls);  // h0[s-1] = slot s
      __syncthreads();
      {
        DECL_ACC
        KSTEPB(qe0, qe1, qe2, qe3, 0, 0)
        KSTEPB(qe0, qe1, qe2, qe3, 256, 256)
        KSTEPB(qhh0r0, qhh0r1, qhh0r2, qhh0r3, 512, 0)
        KSTEPB(qhh0r0, qhh0r1, qhh0r2, qhh0r3, 768, 256)
        KSTEPB(qhh0r0, qhh0r1, qhh0r2, qhh0r3, 1024, 512)
        KSTEPB(qhh0r0, qhh0r1, qhh0r2, qhh0r3, 1280, 768)
        REDUCE_ALL
        WRITE_GLSX(glsA)
      }
      __syncthreads();
      if (tid < 64) {
        const int jp = w4 + gdj;
        float gi = glsA[0][gdj][gb] + cpA0;
        float gf = glsA[1][gdj][gb] + cpA1;
        float gg = glsA[2][gdj][gb] + cpA2;
        float go = glsA[3][gdj][gb] + cpA3;
        c0r = sigf(gf) * c0r + sigf(gi) * tanh_(gg);
        float h = sigf(go) * tanh_(c0r);
        st_cv(x1r + (size_t)(s + 1) * 16384 + gb * 1024 + jp, h);  // slot s+1
      }
    }

    // ---- Phase B: LSTM layer 1 at t = s-1 (x1[s-1] already in LDS cols 512..1535) ----
    if (s >= 1) {
      if (s == 128) stage64k_pl(x1r + (size_t)128 * 16384, 512, tid, xls);  // no phase A
      stage64k_split(h1r + (size_t)(s - 1) * 16384, tid, xls);  // h1[s-2] = slot s-1
      __syncthreads();
      {
        DECL_ACC
        KSTEPB(qih1r0, qih1r1, qih1r2, qih1r3, 512, 0)
        KSTEPB(qih1r0, qih1r1, qih1r2, qih1r3, 768, 256)
        KSTEPB(qih1r0, qih1r1, qih1r2, qih1r3, 1024, 512)
        KSTEPB(qih1r0, qih1r1, qih1r2, qih1r3, 1280, 768)
        KSTEPB(qhh1r0, qhh1r1, qhh1r2, qhh1r3, 0, 0)
        KSTEPB(qhh1r0, qhh1r1, qhh1r2, qhh1r3, 256, 256)
        KSTEPB(qhh1r0, qhh1r1, qhh1r2, qhh1r3, 1536, 512)
        KSTEPB(qhh1r0, qhh1r1, qhh1r2, qhh1r3, 1792, 768)
        REDUCE_ALL
        WRITE_GLSX(glsB)
      }
      __syncthreads();
      if (tid < 64) {
        const int jp = w4 + gdj;
        float gi = glsB[0][gdj][gb] + cpB0;
        float gf = glsB[1][gdj][gb] + cpB1;
        float gg = glsB[2][gdj][gb] + cpB2;
        float go = glsB[3][gdj][gb] + cpB3;
        c1r = sigf(gf) * c1r + sigf(gi) * tanh_(gg);
        float h = sigf(go) * tanh_(c1r);
        st_cv(h1r + (size_t)s * 16384 + gb * 1024 + jp, h);  // slot s
        out2b[((s - 1) * 16 + gb) * 1024 + jp] = f2bf(tanh_(h));
      }
    }

    gsyncf(++step, bar);  // single grid barrier per macro-step
  }
}

// logits GEMM: A bf16 [2048][1024]; B fp32 [32000][1024] (cvt per tile); C fp32.
__global__ __launch_bounds__(256, 2) void fc_gemm_mfma(
    const u16* __restrict__ A, const float* __restrict__ Bw,
    const float* __restrict__ bias, float* __restrict__ C) {
  __shared__ __align__(16) u16 Al[128][40];
  __shared__ __align__(16) u16 Bl[128][40];

  const int tid = threadIdx.x;
  const int m0 = blockIdx.x * 128;
  const int n0 = blockIdx.y * 128;
  const int wave = tid >> 6;
  const int lane = tid & 63;
  const int wm = (wave & 1) * 64;
  const int wn = (wave >> 1) * 64;
  const int fr = lane & 15;
  const int ks = lane >> 4;

  const int srow = tid >> 1;
  const int sh16 = (tid & 1) * 16;

  const u16* Ag = A + (size_t)(m0 + srow) * 1024 + sh16;
  const float* Bg = Bw + (size_t)(n0 + srow) * 1024 + sh16;

  f32x4 acc[4][4] = {};

  for (int k0 = 0; k0 < 1024; k0 += 32) {
    uint4 a0 = *(const uint4*)(Ag + k0);
    uint4 a1 = *(const uint4*)(Ag + k0 + 8);
    float bfv[16];
    *(float4*)&bfv[0] = *(const float4*)(Bg + k0);
    *(float4*)&bfv[4] = *(const float4*)(Bg + k0 + 4);
    *(float4*)&bfv[8] = *(const float4*)(Bg + k0 + 8);
    *(float4*)&bfv[12] = *(const float4*)(Bg + k0 + 12);
    u16 bu[16];
#pragma unroll
    for (int u = 0; u < 16; ++u) bu[u] = f2bf(bfv[u]);

    __syncthreads();
    *(uint4*)&Al[srow][sh16] = a0;
    *(uint4*)&Al[srow][sh16 + 8] = a1;
    *(uint4*)&Bl[srow][sh16] = *(uint4*)&bu[0];
    *(uint4*)&Bl[srow][sh16 + 8] = *(uint4*)&bu[8];
    __syncthreads();

    bf16x8 af[4], bf[4];
#pragma unroll
    for (int i = 0; i < 4; ++i) af[i] = *(const bf16x8*)&Al[wm + i * 16 + fr][ks * 8];
#pragma unroll
    for (int j = 0; j < 4; ++j) bf[j] = *(const bf16x8*)&Bl[wn + j * 16 + fr][ks * 8];
#pragma unroll
    for (int i = 0; i < 4; ++i)
#pragma unroll
      for (int j = 0; j < 4; ++j)
        acc[i][j] = __builtin_amdgcn_mfma_f32_16x16x32_bf16(af[i], bf[j], acc[i][j], 0, 0, 0);
  }

  float bj[4];
#pragma unroll
  for (int j = 0; j < 4; ++j) bj[j] = bias[n0 + wn + j * 16 + fr];

  const int mrb = (lane >> 4) * 4;
#pragma unroll
  for (int i = 0; i < 4; ++i) {
#pragma unroll
    for (int r = 0; r < 4; ++r) {
      const int m = m0 + wm + i * 16 + mrb + r;
      float* dst = C + ((size_t)(m & 15) * 128 + (m >> 4)) * 32000;
#pragma unroll
      for (int j = 0; j < 4; ++j) {
        dst[n0 + wn + j * 16 + fr] = acc[i][j][r] + bj[j];
      }
    }
  }
}

extern "C" void kernel_launch(void* const* d_in, const int* in_sizes, int n_in,
                              void* d_out, int out_size, void* d_ws, size_t ws_size,
                              hipStream_t stream) {
  const float* enc_h = (const float*)d_in[0];
  const float* enc_c = (const float*)d_in[1];
  const int* tgt = (const int*)d_in[2];
  const float* emb = (const float*)d_in[3];
  const float* wih0 = (const float*)d_in[4];
  const float* whh0 = (const float*)d_in[5];
  const float* bih0 = (const float*)d_in[6];
  const float* bhh0 = (const float*)d_in[7];
  const float* wih1 = (const float*)d_in[8];
  const float* whh1 = (const float*)d_in[9];
  const float* bih1 = (const float*)d_in[10];
  const float* bhh1 = (const float*)d_in[11];
  const float* fcw = (const float*)d_in[12];
  const float* fcb = (const float*)d_in[13];
  float* logits = (float*)d_out;

  unsigned* bar = (unsigned*)d_ws;  // 32 KB barrier region
  hipMemsetAsync(d_ws, 0, 64 + 256 * 64, stream);

  // ws layout (~50.5 MB total):
  u16* wb_e = (u16*)((char*)d_ws + 32768);  // 4096*512  emb cols of w_ih0
  u16* wb_hh0 = wb_e + 2097152;             // 4096*1024
  u16* wb_ih1 = wb_hh0 + 4194304;
  u16* wb_hh1 = wb_ih1 + 4194304;
  float* x1r = (float*)(wb_hh1 + 4194304);  // 129 slabs * 16384 f
  float* h1r = x1r + 2113536;               // 129 slabs * 16384 f
  u16* out2b = (u16*)(h1r + 2113536);       // 2048*1024 bf16

  prep_bf16_s<<<1024, 256, 0, stream>>>(wih0, wb_e, 262144);
  prep_bf16<<<2048, 256, 0, stream>>>(whh0, wb_hh0, 524288);
  prep_bf16<<<2048, 256, 0, stream>>>(wih1, wb_ih1, 524288);
  prep_bf16<<<2048, 256, 0, stream>>>(whh1, wb_hh1, 524288);
  dec_seq_pl<<<NBLK, 512, 0, stream>>>(enc_h, enc_c, tgt, emb, wih0, bih0, bhh0,
                                       bih1, bhh1, wb_e, wb_hh0, wb_ih1, wb_hh1,
                                       x1r, h1r, out2b, bar);
  fc_gemm_mfma<<<dim3(16, 250), 256, 0, stream>>>(out2b, fcw, fcb, logits);
}

// Round 9
// 1098.441 us; speedup vs baseline: 3.2467x; 2.8288x over previous
//
#include <hip/hip_runtime.h>

// Decoder: B=16, T=128, V=32000, E=512, H=1024 (2 LSTM layers), CTX=2048.
// R9: weights LDS-RESIDENT + MFMA recurrence.
//   Prior rounds pinned ~11.5us/step on per-step weight refetch (L2 thrash at
//   3.67MB/4MiB + stream pollution; FETCH 2.2GB/dispatch). Now each block's
//   112KB bf16 weight slice is converted fp32->bf16 ONCE into LDS; per-step
//   gate GEMM is [16xK]x[Kx16] via mfma_f32_16x16x32_bf16 (wave0=L0, wave1=L1).
//   x/h move through bf16 write-once rings, staged in 512-col chunks (dbuf).
//   prep_emb pre-gathers token embeddings (bf16); prep_ctx precomputes the
//   fp32 ctx projection into cp[4096][16].
// fc_gemm_mfma: bf16 MFMA GEMM -> [16][128][32000] logits (~125us).

#define NBLK 256

typedef float f32x4 __attribute__((ext_vector_type(4)));
typedef __bf16 bf16x8 __attribute__((ext_vector_type(8)));
typedef unsigned short u16;

__device__ __forceinline__ float sigf(float x) { return 1.0f / (1.0f + __expf(-x)); }
__device__ __forceinline__ float tanh_(float x) {
  x = fminf(15.0f, fmaxf(-15.0f, x));
  float e = __expf(2.0f * x);
  return (e - 1.0f) / (e + 1.0f);
}

__device__ __forceinline__ u16 f2bf(float f) {
  __bf16 h = (__bf16)f;  // RNE
  return __builtin_bit_cast(u16, h);
}

// Coherent (write-through) stores.
__device__ __forceinline__ void st_cv16(u16* p, u16 v) {
  unsigned vv = v;
  asm volatile("global_store_short %0, %1, off sc0 sc1" :: "v"(p), "v"(vv) : "memory");
}

// Flag publish: drain own data stores, then plain sc0/sc1 flag store.
__device__ __forceinline__ void flag_store(unsigned* p, unsigned v) {
  asm volatile(
      "s_waitcnt vmcnt(0)\n\t"
      "global_store_dword %0, %1, off sc0 sc1"
      :: "v"(p), "v"(v) : "memory");
}

// 4 bypass flag loads in flight (no atomic lowering -> no buffer_inv).
__device__ __forceinline__ void ld4_flags(const unsigned* p, unsigned& a, unsigned& b,
                                          unsigned& c, unsigned& d) {
  asm volatile(
      "global_load_dword %0, %4, off sc0 sc1\n\t"
      "global_load_dword %1, %5, off sc0 sc1\n\t"
      "global_load_dword %2, %6, off sc0 sc1\n\t"
      "global_load_dword %3, %7, off sc0 sc1\n\t"
      "s_waitcnt vmcnt(0)"
      : "=&v"(a), "=&v"(b), "=&v"(c), "=&v"(d)
      : "v"(p), "v"(p + 16), "v"(p + 32), "v"(p + 48)
      : "memory");
}

// Flat one-hop pure-asm barrier: block's wave0 publishes flag, polls all 256.
__device__ __forceinline__ void gsyncf(unsigned step, unsigned* bar) {
  __syncthreads();
  const int tid = threadIdx.x;
  if (tid == 0) flag_store(bar + 16 + blockIdx.x * 16, step);
  if (tid < 64) {
    const unsigned* base = bar + 16 + tid * 64;  // 4 flags per lane
    for (;;) {
      unsigned a, b, c, d;
      ld4_flags(base, a, b, c, d);
      bool mine = (a >= step) & (b >= step) & (c >= step) & (d >= step);
      if (__all(mine)) break;
      __builtin_amdgcn_s_sleep(1);
    }
    asm volatile("" ::: "memory");
  }
  __syncthreads();
}

__device__ __forceinline__ void dot4(float& a, float4 wv, float4 xv) {
  a = fmaf(wv.x, xv.x, a);
  a = fmaf(wv.y, xv.y, a);
  a = fmaf(wv.z, xv.z, a);
  a = fmaf(wv.w, xv.w, a);
}

// 16 chained MFMAs over one 512-col chunk. fr = lane&15, ks8 = (lane>>4)*8.
#define MFMA16(ACC, XB, WM, WOFF)                                           \
  _Pragma("unroll")                                                         \
  for (int mm = 0; mm < 16; ++mm) {                                         \
    bf16x8 av = *(const bf16x8*)&XB[fr][mm * 32 + ks8];                     \
    bf16x8 bv = *(const bf16x8*)&WM[fr][(WOFF) + mm * 32 + ks8];            \
    ACC = __builtin_amdgcn_mfma_f32_16x16x32_bf16(av, bv, ACC, 0, 0, 0);    \
  }

// ---- prep: gather token embeddings as bf16: x0b[t][b][512] ----
__global__ void prep_emb(const int* __restrict__ tgt, const float* __restrict__ emb,
                         u16* __restrict__ x0b) {
  const int g = blockIdx.x * blockDim.x + threadIdx.x;  // 131072 total
  const int col8 = (g & 63) * 8;
  const int tb = g >> 6;            // 0..2047
  const int t = tb >> 4, b = tb & 15;
  const int tok = (t == 0) ? 1 : tgt[b * 128 + (t - 1)];
  const float* s = emb + (size_t)tok * 512 + col8;
  float4 a = *(const float4*)s;
  float4 bb = *(const float4*)(s + 4);
  __align__(16) u16 r[8] = {f2bf(a.x), f2bf(a.y), f2bf(a.z), f2bf(a.w),
                            f2bf(bb.x), f2bf(bb.y), f2bf(bb.z), f2bf(bb.w)};
  *(uint4*)(x0b + (size_t)tb * 512 + col8) = *(uint4*)r;
}

// ---- prep: fp32 ctx projection cp[j][b] = sum_k wih0[j][512+k]*ctx[b][k] ----
__global__ __launch_bounds__(256, 1) void prep_ctx(const float* __restrict__ enc_h,
                                                   const float* __restrict__ wih0,
                                                   float* __restrict__ cp) {
  __shared__ float ctx[16][2052];
  const int tid = threadIdx.x;
#pragma unroll
  for (int c = 0; c < 32; ++c) {
    int f4 = tid + c * 256;
    int b = f4 >> 9, kq = f4 & 511;
    *(float4*)&ctx[b][kq * 4] =
        *(const float4*)(enc_h + (kq >> 7) * 8192 + b * 512 + (kq & 127) * 4);
  }
  __syncthreads();
  const int jr = tid >> 4, b = tid & 15;
  const int j = blockIdx.x * 16 + jr;
  const float* w = wih0 + (size_t)j * 2560 + 512;
  float a0 = 0.f, a1 = 0.f, a2 = 0.f, a3 = 0.f;
  for (int k = 0; k < 2048; k += 16) {
    float4 w0 = *(const float4*)(w + k);
    float4 w1 = *(const float4*)(w + k + 4);
    float4 w2 = *(const float4*)(w + k + 8);
    float4 w3 = *(const float4*)(w + k + 12);
    float4 x0 = *(const float4*)&ctx[b][k];
    float4 x1 = *(const float4*)&ctx[b][k + 4];
    float4 x2 = *(const float4*)&ctx[b][k + 8];
    float4 x3 = *(const float4*)&ctx[b][k + 12];
    dot4(a0, w0, x0); dot4(a1, w1, x1); dot4(a2, w2, x2); dot4(a3, w3, x3);
  }
  cp[(size_t)j * 16 + b] = a0 + a1 + a2 + a3;
}

// ---------------- persistent MFMA decoder ----------------
// Rings (bf16, write-once): xr slot t+1 = h0/x1 at step t (slot 0 = init h0);
//                           h1r slot t+1 = h1 at step t  (slot 0 = init h1).
__global__ __launch_bounds__(512, 1) void dec_seq_mf(
    const float* __restrict__ enc_h, const float* __restrict__ enc_c,
    const float* __restrict__ wih0, const float* __restrict__ whh0,
    const float* __restrict__ wih1, const float* __restrict__ whh1,
    const float* __restrict__ bih0, const float* __restrict__ bhh0,
    const float* __restrict__ bih1, const float* __restrict__ bhh1,
    const float* __restrict__ cp, const u16* __restrict__ x0b,
    u16* __restrict__ xr, u16* __restrict__ h1r,
    u16* __restrict__ out2b, unsigned* bar) {
  // strides: 16B-aligned rows, dword-stride = 4 mod 32 (2-4 way banks, ok)
  __shared__ u16 Wa[16][1544];      // L0 weights: [p][0..511]=emb, [512..1535]=hh0
  __shared__ u16 Wb[16][2056];      // L1 weights: [p][0..1023]=ih1, [1024..2047]=hh1
  __shared__ u16 xc[2][16][520];    // x chunk double-buffer (512 cols)
  __shared__ float glsA[16][17];    // [p][batch]
  __shared__ float glsB[16][17];

  const int tid = threadIdx.x;
  const int wgid = blockIdx.x;
  const int w4 = wgid * 4;
  const int lane = tid & 63;
  const int wave = tid >> 6;
  const int fr = lane & 15;
  const int ks8 = (lane >> 4) * 8;
  unsigned step = 0;

  // ---- INIT: convert this block's weight slice fp32 -> bf16 into LDS ----
  {
    const int row = tid >> 5;                                // p = gate*4+u
    const int j = (row >> 2) * 1024 + w4 + (row & 3);
    {  // Wa[row][0..511] = wih0[j][0..511]
      const int c = (tid & 31) * 16;
      const float* s = wih0 + (size_t)j * 2560 + c;
      __align__(16) u16 r[16];
#pragma unroll
      for (int q = 0; q < 4; ++q) {
        float4 v = *(const float4*)(s + q * 4);
        r[q * 4 + 0] = f2bf(v.x); r[q * 4 + 1] = f2bf(v.y);
        r[q * 4 + 2] = f2bf(v.z); r[q * 4 + 3] = f2bf(v.w);
      }
      *(uint4*)&Wa[row][c] = *(uint4*)&r[0];
      *(uint4*)&Wa[row][c + 8] = *(uint4*)&r[8];
    }
    {  // Wa[row][512..1535] = whh0[j][0..1023]
      const int c = (tid & 31) * 32;
      const float* s = whh0 + (size_t)j * 1024 + c;
      __align__(16) u16 r[32];
#pragma unroll
      for (int q = 0; q < 8; ++q) {
        float4 v = *(const float4*)(s + q * 4);
        r[q * 4 + 0] = f2bf(v.x); r[q * 4 + 1] = f2bf(v.y);
        r[q * 4 + 2] = f2bf(v.z); r[q * 4 + 3] = f2bf(v.w);
      }
#pragma unroll
      for (int q = 0; q < 4; ++q) *(uint4*)&Wa[row][512 + c + q * 8] = *(uint4*)&r[q * 8];
    }
    {  // Wb[row][0..1023] = wih1[j][0..1023]
      const int c = (tid & 31) * 32;
      const float* s = wih1 + (size_t)j * 1024 + c;
      __align__(16) u16 r[32];
#pragma unroll
      for (int q = 0; q < 8; ++q) {
        float4 v = *(const float4*)(s + q * 4);
        r[q * 4 + 0] = f2bf(v.x); r[q * 4 + 1] = f2bf(v.y);
        r[q * 4 + 2] = f2bf(v.z); r[q * 4 + 3] = f2bf(v.w);
      }
#pragma unroll
      for (int q = 0; q < 4; ++q) *(uint4*)&Wb[row][c + q * 8] = *(uint4*)&r[q * 8];
    }
    {  // Wb[row][1024..2047] = whh1[j][0..1023]
      const int c = (tid & 31) * 32;
      const float* s = whh1 + (size_t)j * 1024 + c;
      __align__(16) u16 r[32];
#pragma unroll
      for (int q = 0; q < 8; ++q) {
        float4 v = *(const float4*)(s + q * 4);
        r[q * 4 + 0] = f2bf(v.x); r[q * 4 + 1] = f2bf(v.y);
        r[q * 4 + 2] = f2bf(v.z); r[q * 4 + 3] = f2bf(v.w);
      }
#pragma unroll
      for (int q = 0; q < 4; ++q) *(uint4*)&Wb[row][1024 + c + q * 8] = *(uint4*)&r[q * 8];
    }
  }

  // ---- INIT per-thread gate state (tid<64: unit gdj, batch gb) ----
  const int gdj = tid >> 4;
  const int gb = tid & 15;
  float cpA0 = 0.f, cpA1 = 0.f, cpA2 = 0.f, cpA3 = 0.f;
  float cpB0 = 0.f, cpB1 = 0.f, cpB2 = 0.f, cpB3 = 0.f;
  float c0r = 0.f, c1r = 0.f;
  if (tid < 64) {
    const int jp = w4 + gdj;
    cpA0 = cp[(size_t)(jp) * 16 + gb] + bih0[jp] + bhh0[jp];
    cpA1 = cp[(size_t)(1024 + jp) * 16 + gb] + bih0[1024 + jp] + bhh0[1024 + jp];
    cpA2 = cp[(size_t)(2048 + jp) * 16 + gb] + bih0[2048 + jp] + bhh0[2048 + jp];
    cpA3 = cp[(size_t)(3072 + jp) * 16 + gb] + bih0[3072 + jp] + bhh0[3072 + jp];
    cpB0 = bih1[jp] + bhh1[jp];
    cpB1 = bih1[1024 + jp] + bhh1[1024 + jp];
    cpB2 = bih1[2048 + jp] + bhh1[2048 + jp];
    cpB3 = bih1[3072 + jp] + bhh1[3072 + jp];
    const int dir = jp >> 9, e = jp & 511;
    c0r = enc_c[dir * 8192 + gb * 512 + e];
    c1r = enc_c[(2 + dir) * 8192 + gb * 512 + e];
    st_cv16(xr + gb * 1024 + jp, f2bf(enc_h[dir * 8192 + gb * 512 + e]));
    st_cv16(h1r + gb * 1024 + jp, f2bf(enc_h[(2 + dir) * 8192 + gb * 512 + e]));
  }
  gsyncf(++step, bar);

  // staging coords: 512 threads cover 16 rows x 512 cols (16 bf16/thread)
  const int srow = tid >> 5;
  const int scol = (tid & 31) * 16;

  // ---- MAIN LOOP: 129 macro-steps; phase A = L0[t=s], phase B = L1[t=s-1] ----
  for (int s = 0; s < 129; ++s) {
    // prefetch all chunk loads to registers (plain cached; rings write-once)
    uint4 rA0a = {}, rA0b = {}, rB2a = {}, rB2b = {}, rB3a = {}, rB3b = {};
    uint4 rA1a, rA1b, rA2a, rA2b;
    {
      const u16* slotS = xr + (size_t)s * 16384 + srow * 1024;
      rA1a = *(const uint4*)(slotS + scol);
      rA1b = *(const uint4*)(slotS + scol + 8);
      rA2a = *(const uint4*)(slotS + 512 + scol);
      rA2b = *(const uint4*)(slotS + 512 + scol + 8);
      if (s < 128) {
        const u16* sE = x0b + (size_t)s * 8192 + srow * 512;
        rA0a = *(const uint4*)(sE + scol);
        rA0b = *(const uint4*)(sE + scol + 8);
      }
      if (s >= 1) {
        const u16* sH = h1r + (size_t)(s - 1) * 16384 + srow * 1024;
        rB2a = *(const uint4*)(sH + scol);
        rB2b = *(const uint4*)(sH + scol + 8);
        rB3a = *(const uint4*)(sH + 512 + scol);
        rB3b = *(const uint4*)(sH + 512 + scol + 8);
      }
    }
    f32x4 accA = {0.f, 0.f, 0.f, 0.f}, accB = {0.f, 0.f, 0.f, 0.f};

    if (s < 128) {  // pre-phase: A0 (emb chunk) -> buf0
      *(uint4*)&xc[0][srow][scol] = rA0a;
      *(uint4*)&xc[0][srow][scol + 8] = rA0b;
    }
    __syncthreads();
    // ph0: mfma buf0 (A emb); write A1 (= x slot s, cols 0..511) -> buf1
    *(uint4*)&xc[1][srow][scol] = rA1a;
    *(uint4*)&xc[1][srow][scol + 8] = rA1b;
    if (wave == 0 && s < 128) { MFMA16(accA, xc[0], Wa, 0) }
    __syncthreads();
    // ph1: mfma buf1 (A hh0[0:512] + B ih1[0:512]); write A2 -> buf0
    *(uint4*)&xc[0][srow][scol] = rA2a;
    *(uint4*)&xc[0][srow][scol + 8] = rA2b;
    if (wave == 0 && s < 128) { MFMA16(accA, xc[1], Wa, 512) }
    if (wave == 1 && s >= 1) { MFMA16(accB, xc[1], Wb, 0) }
    __syncthreads();
    // ph2: mfma buf0 (A hh0[512:1024] + B ih1[512:1024]); write B2 -> buf1
    if (s >= 1) {
      *(uint4*)&xc[1][srow][scol] = rB2a;
      *(uint4*)&xc[1][srow][scol + 8] = rB2b;
    }
    if (wave == 0 && s < 128) { MFMA16(accA, xc[0], Wa, 1024) }
    if (wave == 1 && s >= 1) { MFMA16(accB, xc[0], Wb, 512) }
    __syncthreads();
    // ph3: mfma buf1 (B hh1[0:512]); write B3 -> buf0
    if (s >= 1) {
      *(uint4*)&xc[0][srow][scol] = rB3a;
      *(uint4*)&xc[0][srow][scol + 8] = rB3b;
    }
    if (wave == 1 && s >= 1) { MFMA16(accB, xc[1], Wb, 1024) }
    __syncthreads();
    // ph4: mfma buf0 (B hh1[512:1024]); write acc tiles to LDS
    if (wave == 1 && s >= 1) { MFMA16(accB, xc[0], Wb, 1536) }
    if (wave == 0 && s < 128) {
#pragma unroll
      for (int r = 0; r < 4; ++r) glsA[fr][(lane >> 4) * 4 + r] = accA[r];
    }
    if (wave == 1 && s >= 1) {
#pragma unroll
      for (int r = 0; r < 4; ++r) glsB[fr][(lane >> 4) * 4 + r] = accB[r];
    }
    __syncthreads();
    // epilogue: gating + state update + ring stores (wave0 lanes)
    if (tid < 64) {
      const int jp = w4 + gdj;
      if (s < 128) {
        float gi = glsA[gdj][gb] + cpA0;
        float gf = glsA[4 + gdj][gb] + cpA1;
        float gg = glsA[8 + gdj][gb] + cpA2;
        float go = glsA[12 + gdj][gb] + cpA3;
        c0r = sigf(gf) * c0r + sigf(gi) * tanh_(gg);
        float h = sigf(go) * tanh_(c0r);
        st_cv16(xr + (size_t)(s + 1) * 16384 + gb * 1024 + jp, f2bf(h));
      }
      if (s >= 1) {
        float gi = glsB[gdj][gb] + cpB0;
        float gf = glsB[4 + gdj][gb] + cpB1;
        float gg = glsB[8 + gdj][gb] + cpB2;
        float go = glsB[12 + gdj][gb] + cpB3;
        c1r = sigf(gf) * c1r + sigf(gi) * tanh_(gg);
        float h = sigf(go) * tanh_(c1r);
        st_cv16(h1r + (size_t)s * 16384 + gb * 1024 + jp, f2bf(h));
        out2b[((s - 1) * 16 + gb) * 1024 + jp] = f2bf(tanh_(h));
      }
    }
    gsyncf(++step, bar);
  }
}

// logits GEMM: A bf16 [2048][1024]; B fp32 [32000][1024] (cvt per tile); C fp32.
__global__ __launch_bounds__(256, 2) void fc_gemm_mfma(
    const u16* __restrict__ A, const float* __restrict__ Bw,
    const float* __restrict__ bias, float* __restrict__ C) {
  __shared__ __align__(16) u16 Al[128][40];
  __shared__ __align__(16) u16 Bl[128][40];

  const int tid = threadIdx.x;
  const int m0 = blockIdx.x * 128;
  const int n0 = blockIdx.y * 128;
  const int wave = tid >> 6;
  const int lane = tid & 63;
  const int wm = (wave & 1) * 64;
  const int wn = (wave >> 1) * 64;
  const int fr = lane & 15;
  const int ks = lane >> 4;

  const int srow = tid >> 1;
  const int sh16 = (tid & 1) * 16;

  const u16* Ag = A + (size_t)(m0 + srow) * 1024 + sh16;
  const float* Bg = Bw + (size_t)(n0 + srow) * 1024 + sh16;

  f32x4 acc[4][4] = {};

  for (int k0 = 0; k0 < 1024; k0 += 32) {
    uint4 a0 = *(const uint4*)(Ag + k0);
    uint4 a1 = *(const uint4*)(Ag + k0 + 8);
    float bfv[16];
    *(float4*)&bfv[0] = *(const float4*)(Bg + k0);
    *(float4*)&bfv[4] = *(const float4*)(Bg + k0 + 4);
    *(float4*)&bfv[8] = *(const float4*)(Bg + k0 + 8);
    *(float4*)&bfv[12] = *(const float4*)(Bg + k0 + 12);
    u16 bu[16];
#pragma unroll
    for (int u = 0; u < 16; ++u) bu[u] = f2bf(bfv[u]);

    __syncthreads();
    *(uint4*)&Al[srow][sh16] = a0;
    *(uint4*)&Al[srow][sh16 + 8] = a1;
    *(uint4*)&Bl[srow][sh16] = *(uint4*)&bu[0];
    *(uint4*)&Bl[srow][sh16 + 8] = *(uint4*)&bu[8];
    __syncthreads();

    bf16x8 af[4], bf[4];
#pragma unroll
    for (int i = 0; i < 4; ++i) af[i] = *(const bf16x8*)&Al[wm + i * 16 + fr][ks * 8];
#pragma unroll
    for (int j = 0; j < 4; ++j) bf[j] = *(const bf16x8*)&Bl[wn + j * 16 + fr][ks * 8];
#pragma unroll
    for (int i = 0; i < 4; ++i)
#pragma unroll
      for (int j = 0; j < 4; ++j)
        acc[i][j] = __builtin_amdgcn_mfma_f32_16x16x32_bf16(af[i], bf[j], acc[i][j], 0, 0, 0);
  }

  float bj[4];
#pragma unroll
  for (int j = 0; j < 4; ++j) bj[j] = bias[n0 + wn + j * 16 + fr];

  const int mrb = (lane >> 4) * 4;
#pragma unroll
  for (int i = 0; i < 4; ++i) {
#pragma unroll
    for (int r = 0; r < 4; ++r) {
      const int m = m0 + wm + i * 16 + mrb + r;
      float* dst = C + ((size_t)(m & 15) * 128 + (m >> 4)) * 32000;
#pragma unroll
      for (int j = 0; j < 4; ++j) {
        dst[n0 + wn + j * 16 + fr] = acc[i][j][r] + bj[j];
      }
    }
  }
}

extern "C" void kernel_launch(void* const* d_in, const int* in_sizes, int n_in,
                              void* d_out, int out_size, void* d_ws, size_t ws_size,
                              hipStream_t stream) {
  const float* enc_h = (const float*)d_in[0];
  const float* enc_c = (const float*)d_in[1];
  const int* tgt = (const int*)d_in[2];
  const float* emb = (const float*)d_in[3];
  const float* wih0 = (const float*)d_in[4];
  const float* whh0 = (const float*)d_in[5];
  const float* bih0 = (const float*)d_in[6];
  const float* bhh0 = (const float*)d_in[7];
  const float* wih1 = (const float*)d_in[8];
  const float* whh1 = (const float*)d_in[9];
  const float* bih1 = (const float*)d_in[10];
  const float* bhh1 = (const float*)d_in[11];
  const float* fcw = (const float*)d_in[12];
  const float* fcb = (const float*)d_in[13];
  float* logits = (float*)d_out;

  unsigned* bar = (unsigned*)d_ws;  // 32 KB barrier region
  hipMemsetAsync(d_ws, 0, 64 + 256 * 64, stream);

  // ws layout (~14.6 MB):
  float* cp = (float*)((char*)d_ws + 32768);  // 4096*16 f32 = 256 KB
  u16* x0b = (u16*)(cp + 65536);              // 2048*512  bf16 = 2 MB
  u16* xr = x0b + 1048576;                    // 129*16384 bf16 = 4.125 MB
  u16* h1r = xr + 2113536;                    // 129*16384 bf16 = 4.125 MB
  u16* out2b = h1r + 2113536;                 // 2048*1024 bf16 = 4 MB

  prep_emb<<<512, 256, 0, stream>>>(tgt, emb, x0b);
  prep_ctx<<<256, 256, 0, stream>>>(enc_h, wih0, cp);
  dec_seq_mf<<<NBLK, 512, 0, stream>>>(enc_h, enc_c, wih0, whh0, wih1, whh1,
                                       bih0, bhh0, bih1, bhh1, cp, x0b,
                                       xr, h1r, out2b, bar);
  fc_gemm_mfma<<<dim3(16, 250), 256, 0, stream>>>(out2b, fcw, fcb, logits);
}